// Round 10
// baseline (111.915 us; speedup 1.0000x reference)
//
#include <hip/hip_runtime.h>

typedef __bf16 bf16;
typedef __attribute__((ext_vector_type(8))) short short8;
typedef __attribute__((ext_vector_type(4))) short short4v;
typedef __attribute__((ext_vector_type(4))) float floatx4;
typedef __attribute__((ext_vector_type(16))) float floatx16;

#define DEVINL __device__ __forceinline__

// async global->LDS, 16B per lane. LDS dest = wave-uniform base + lane*16.
DEVINL void gll16(const void* g, void* l) {
  __builtin_amdgcn_global_load_lds((const __attribute__((address_space(1))) void*)g,
                                   (__attribute__((address_space(3))) void*)l, 16, 0, 0);
}

DEVINL float fast_exp2(float x) { return __builtin_amdgcn_exp2f(x); }

// scale * log2(e), folded into Q at projection time
#define QSCALE 0.18033688011112042f

// ---------------- fused prep: x->bf16 (blocks 0..2047) + weight transposes (2048..3071) ----
__global__ __launch_bounds__(256) void prep_all(const float* __restrict__ x,
                                                const float* __restrict__ Wq,
                                                const float* __restrict__ Wk,
                                                const float* __restrict__ Wv,
                                                const float* __restrict__ Wo,
                                                bf16* __restrict__ x_bf,
                                                bf16* __restrict__ WbigT,
                                                bf16* __restrict__ WoT) {
  __shared__ float tile[64][65];
  int bid = blockIdx.x;
  if (bid < 2048) {
    int i = (bid * 256 + threadIdx.x) * 8;
    float4 a = *(const float4*)(x + i);
    float4 b = *(const float4*)(x + i + 4);
    union { bf16 h[8]; short8 s; } u;
    u.h[0] = (bf16)a.x; u.h[1] = (bf16)a.y; u.h[2] = (bf16)a.z; u.h[3] = (bf16)a.w;
    u.h[4] = (bf16)b.x; u.h[5] = (bf16)b.y; u.h[6] = (bf16)b.z; u.h[7] = (bf16)b.w;
    *(short8*)(x_bf + i) = u.s;
    return;
  }
  int t = bid - 2048;
  int which = t >> 8;         // 0..3
  t &= 255;
  const float* in;
  bf16* out;
  int C, tilesC, tilesPerBatch;
  long inStride;
  if (which < 3) {
    in = which == 0 ? Wq : (which == 1 ? Wk : Wv);
    out = WbigT + (long)which * 1024 * 1024;
    C = 64; tilesC = 1; tilesPerBatch = 16; inStride = 65536;
  } else {
    in = Wo; out = WoT;
    C = 1024; tilesC = 16; tilesPerBatch = 256; inStride = 0;
  }
  int batch = t / tilesPerBatch;
  int tt = t % tilesPerBatch;
  int ri = tt / tilesC, ci = tt % tilesC;
  const float* src = in + batch * inStride;
  bf16* dst = out + batch * (long)65536 * (which < 3 ? 1 : 0);
  int tx = threadIdx.x & 63, ty = threadIdx.x >> 6;
#pragma unroll
  for (int i = 0; i < 16; i++) {
    int r = ty + i * 4;
    tile[r][tx] = src[(long)(ri * 64 + r) * C + ci * 64 + tx];
  }
  __syncthreads();
#pragma unroll
  for (int i = 0; i < 16; i++) {
    int c = ty + i * 4;
    dst[(long)(ci * 64 + c) * 1024 + ri * 64 + tx] = (bf16)tile[tx][c];
  }
}

// ---------------- QKV GEMM: 256x256 tile, BK=64, 8-phase counted-vmcnt schedule --------
__global__ __launch_bounds__(512, 2) void gemm256_qkv(const bf16* __restrict__ A,
                                                      const bf16* __restrict__ BT,
                                                      bf16* __restrict__ q_ws,
                                                      bf16* __restrict__ k_ws,
                                                      bf16* __restrict__ v_ws) {
  extern __shared__ char lds[];
  int swz = (blockIdx.x & 7) * 24 + (blockIdx.x >> 3);  // grid 192 = 16 x 12, XCD swizzle
  int bm = swz / 12, bn = swz % 12;
  int tid = threadIdx.x, lane = tid & 63, wid = tid >> 6;
  int wm = wid >> 2, wn = wid & 3;
  int ql = lane & 15, g = lane >> 4;
  int sw = (ql & 7) << 4;
  int hB = wn >> 1;
  char* ldsA = lds;            // [slot][half] 2*2*16KB
  char* ldsB = lds + 65536;

  const char* Abase = (const char*)A + (long)bm * 256 * 2048;
  const char* Bbase = (const char*)BT + (long)bn * 256 * 2048;
  int scb = ((tid & 7) * 16) ^ (((tid >> 3) & 7) << 4);  // pre-swizzled source col

  floatx4 acc[8][4] = {};
  short8 aF[4], bF[4];

#define STG(dst0, src0, kt_, h_) do {                                              \
    _Pragma("unroll") for (int j_ = 0; j_ < 2; j_++)                               \
      gll16((src0) + (long)((h_) * 128 + j_ * 64 + (tid >> 3)) * 2048              \
                   + (kt_) * 128 + scb,                                            \
            (dst0) + ((kt_) & 1) * 32768 + (h_) * 16384 + j_ * 8192 + wid * 1024); \
  } while (0)
#define LDA(slot_, frh_, kk_) do {                                                 \
    _Pragma("unroll") for (int j_ = 0; j_ < 4; j_++)                               \
      aF[j_] = *(const short8*)(ldsA + (slot_) * 32768 + wm * 16384 +              \
               (((frh_) * 4 + j_) * 16 + ql) * 128 + (((kk_) * 64 + g * 16) ^ sw));\
  } while (0)
#define LDB(slot_, kk_) do {                                                       \
    _Pragma("unroll") for (int f_ = 0; f_ < 4; f_++)                               \
      bF[f_] = *(const short8*)(ldsB + (slot_) * 32768 + hB * 16384 +              \
               ((wn & 1) * 64 + f_ * 16 + ql) * 128 + (((kk_) * 64 + g * 16) ^ sw));\
  } while (0)
#define MFMA16(frh_) do {                                                          \
    __builtin_amdgcn_s_setprio(1);                                                 \
    _Pragma("unroll") for (int j_ = 0; j_ < 4; j_++)                               \
      _Pragma("unroll") for (int f_ = 0; f_ < 4; f_++)                             \
        acc[(frh_) * 4 + j_][f_] = __builtin_amdgcn_mfma_f32_16x16x32_bf16(        \
            aF[j_], bF[f_], acc[(frh_) * 4 + j_][f_], 0, 0, 0);                    \
    __builtin_amdgcn_s_setprio(0);                                                 \
  } while (0)
#define BAR __builtin_amdgcn_s_barrier()
#define LG0 asm volatile("s_waitcnt lgkmcnt(0)" ::: "memory")

  // prologue: B0(0),B1(0),A0(0),A1(0),B0(1) = 10 loads
  STG(ldsB, Bbase, 0, 0); STG(ldsB, Bbase, 0, 1);
  STG(ldsA, Abase, 0, 0); STG(ldsA, Abase, 0, 1);
  STG(ldsB, Bbase, 1, 0);

  for (int it = 0; it < 8; it++) {
    int b1 = 2 * it + 1, a2 = 2 * it + 2, b2 = 2 * it + 3;
    bool more = it < 7;
    // P1 (a, frh0, kk0)
    asm volatile("s_waitcnt vmcnt(2)" ::: "memory");
    BAR;
    LDA(0, 0, 0); LDB(0, 0);
    STG(ldsA, Abase, b1, 0);
    BAR; LG0; MFMA16(0); BAR;
    // P2 (a, frh1, kk0)
    LDA(0, 1, 0);
    STG(ldsA, Abase, b1, 1);
    BAR; LG0; MFMA16(1); BAR;
    // P3 (a, frh0, kk1)
    LDA(0, 0, 1); LDB(0, 1);
    STG(ldsB, Bbase, b1, 1);
    BAR; LG0; MFMA16(0); BAR;
    // P4 (a, frh1, kk1)
    LDA(0, 1, 1);
    if (more) STG(ldsB, Bbase, a2, 0);
    BAR; LG0; MFMA16(1); BAR;
    // P5 (b, frh0, kk0)
    if (more) { asm volatile("s_waitcnt vmcnt(2)" ::: "memory"); }
    else      { asm volatile("s_waitcnt vmcnt(0)" ::: "memory"); }
    BAR;
    LDA(1, 0, 0); LDB(1, 0);
    if (more) STG(ldsB, Bbase, a2, 1);
    BAR; LG0; MFMA16(0); BAR;
    // P6 (b, frh1, kk0)
    LDA(1, 1, 0);
    if (more) STG(ldsA, Abase, a2, 0);
    BAR; LG0; MFMA16(1); BAR;
    // P7 (b, frh0, kk1)
    LDA(1, 0, 1); LDB(1, 1);
    if (more) STG(ldsA, Abase, a2, 1);
    BAR; LG0; MFMA16(0); BAR;
    // P8 (b, frh1, kk1)
    LDA(1, 1, 1);
    if (more) STG(ldsB, Bbase, b2, 0);
    BAR; LG0; MFMA16(1); BAR;
  }
#undef STG
#undef LDA
#undef LDB
#undef MFMA16
#undef BAR
#undef LG0

  if (bn < 8) {
    // ---- Q / K scatter ----
    bf16* dst = (bn < 4) ? q_ws : k_ws;
    float scale = (bn < 4) ? QSCALE : 1.0f;
#pragma unroll
    for (int fr = 0; fr < 8; fr++)
#pragma unroll
      for (int fc = 0; fc < 4; fc++)
#pragma unroll
        for (int i = 0; i < 4; i++) {
          int r = bm * 256 + wm * 128 + fr * 16 + g * 4 + i;
          int c = bn * 256 + wn * 64 + fc * 16 + ql;
          int b = r >> 11, s = r & 2047;
          int h = (c >> 6) & 15, e = c & 63;
          long bh = (long)b * 16 + h;
          dst[(bh * 2048 + s) * 64 + e] = (bf16)(acc[fr][fc][i] * scale);
        }
  } else {
    // ---- V: acc -> LDS (sigma32 = swap key bits 2<->3, + swizzle) -> coalesced V^T stores ----
#pragma unroll
    for (int fr = 0; fr < 8; fr++)
#pragma unroll
      for (int fc = 0; fc < 4; fc++) {
        int local_c = wn * 64 + fc * 16 + ql;        // 0..255 (dv within block)
        int ls0 = wm * 128 + fr * 16 + g * 4;        // 0..255 (s local, 4-aligned)
        // sigma32: within each 64-key group, swap bits 2 and 3 of the key index
        int sp = (ls0 & ~12) | ((ls0 & 4) << 1) | ((ls0 & 8) >> 1);
        union { bf16 hh[4]; short4v s4; } u;
#pragma unroll
        for (int i = 0; i < 4; i++) u.hh[i] = (bf16)acc[fr][fc][i];
        *(short4v*)(lds + local_c * 512 + ((sp * 2) ^ ((local_c & 7) << 4))) = u.s4;
      }
    __syncthreads();
    int b = bm >> 3;
    long sbase = (long)(bm & 7) * 256;
#pragma unroll
    for (int j = 0; j < 16; j++) {
      int local_c = wid * 32 + j * 2 + (lane >> 5);
      int chunk = lane & 31;
      int cg = bn * 256 + local_c;                   // 2048..3071
      int h = (cg >> 6) & 15, e = cg & 63;
      long bh = (long)b * 16 + h;
      char* dstp = (char*)v_ws + ((bh * 64 + e) * 2048 + sbase) * 2 + chunk * 16;
      *(short8*)dstp = *(const short8*)(lds + local_c * 512 + ((chunk * 16) ^ ((local_c & 7) << 4)));
    }
  }
}

// ---------------- GEMM (output projection): 128x128 tile, 4 waves, 2-phase pipelined ----
__global__ __launch_bounds__(256) void gemm_out(const bf16* __restrict__ A,
                                                const bf16* __restrict__ BT,
                                                float* __restrict__ Cout,
                                                int N, int gridN) {
  int cpx = gridDim.x >> 3;
  int swz = (blockIdx.x & 7) * cpx + (blockIdx.x >> 3);
  int bm = swz / gridN, bn = swz % gridN;
  __shared__ char lds[65536];  // A slots @0,16K ; B slots @32K,48K
  int tid = threadIdx.x;
  int lane = tid & 63, wid = tid >> 6;
  int wr = wid >> 1, wc = wid & 1;
  floatx4 acc[4][4] = {};
  const char* Abase = (const char*)A + (long)bm * 128 * 2048;
  const char* Bbase = (const char*)BT + (long)bn * 128 * 2048;
  int scb = ((tid & 7) * 16) ^ (((tid >> 3) & 7) << 4);

#define OSTG(kt_) do {                                                             \
    char* la_ = lds + ((kt_) & 1) * 16384;                                         \
    char* lb_ = lds + 32768 + ((kt_) & 1) * 16384;                                 \
    _Pragma("unroll") for (int q_ = 0; q_ < 4; q_++) {                             \
      gll16(Abase + (long)(q_ * 32 + (tid >> 3)) * 2048 + (kt_) * 128 + scb,       \
            la_ + q_ * 4096 + wid * 1024);                                         \
      gll16(Bbase + (long)(q_ * 32 + (tid >> 3)) * 2048 + (kt_) * 128 + scb,       \
            lb_ + q_ * 4096 + wid * 1024);                                         \
    }                                                                              \
  } while (0)

  OSTG(0);
  for (int kt = 0; kt < 16; kt++) {
    if (kt < 15) {
      OSTG(kt + 1);
      asm volatile("s_waitcnt vmcnt(8)" ::: "memory");
    } else {
      asm volatile("s_waitcnt vmcnt(0)" ::: "memory");
    }
    __builtin_amdgcn_s_barrier();
    char* la = lds + (kt & 1) * 16384;
    char* lb = lds + 32768 + (kt & 1) * 16384;
#pragma unroll
    for (int kk = 0; kk < 2; kk++) {
      short8 a[4], b[4];
#pragma unroll
      for (int mi = 0; mi < 4; mi++) {
        int row = wr * 64 + mi * 16 + (lane & 15);
        int col = (kk * 64 + (lane >> 4) * 16) ^ ((row & 7) << 4);
        a[mi] = *(const short8*)(la + row * 128 + col);
      }
#pragma unroll
      for (int ni = 0; ni < 4; ni++) {
        int row = wc * 64 + ni * 16 + (lane & 15);
        int col = (kk * 64 + (lane >> 4) * 16) ^ ((row & 7) << 4);
        b[ni] = *(const short8*)(lb + row * 128 + col);
      }
#pragma unroll
      for (int mi = 0; mi < 4; mi++)
#pragma unroll
        for (int ni = 0; ni < 4; ni++)
          acc[mi][ni] = __builtin_amdgcn_mfma_f32_16x16x32_bf16(a[mi], b[ni], acc[mi][ni], 0, 0, 0);
    }
    __builtin_amdgcn_s_barrier();
  }
#undef OSTG

#pragma unroll
  for (int mi = 0; mi < 4; mi++)
#pragma unroll
    for (int ni = 0; ni < 4; ni++)
#pragma unroll
      for (int i = 0; i < 4; i++) {
        int r = bm * 128 + wr * 64 + mi * 16 + (lane >> 4) * 4 + i;
        int c = bn * 128 + wc * 64 + ni * 16 + (lane & 15);
        Cout[(long)r * N + c] = acc[mi][ni][i];
      }
}

// ---------------- flash attention: 32x32x16 MFMA, KV-split x2, 1024-thread block --------
// grid 256 (1 block/CU, XCD-bijective). 16 waves = 2 groups of 8; group g covers keys
// [g*1024, g*1024+1024) for the same 256 q-rows (32 q/wave via one 32x32 S^T tile).
// S^T = mfma32(K, Q): lane (q=l&31, h=l>>5) holds S[key][q] for 16 keys/tile at rows
// (reg&3)+8*(reg>>2)+4h (m74-verified C/D map). kappa key-order makes pb[c] = exp2 of
// sa regs 8c..8c+7 (pure in-register P packing); V^T stored with sigma32 (key bits
// 2<->3 swapped) so PV A-fragments are single conflict-free ds_read_b128.
// Max-free softmax; l = VALU tree-sum + one end shfl. 4-deep K/V LDS, vmcnt(2)+barrier
// per leg, PV in-leg. Combine O=O0+O1, l=l0+l1 through dead LDS at the end.
__global__ __launch_bounds__(1024, 4) void attn_kernel(const bf16* __restrict__ q_ws,
                                                       const bf16* __restrict__ k_ws,
                                                       const bf16* __restrict__ v_ws,
                                                       bf16* __restrict__ obuf) {
  extern __shared__ char lds[];  // [grp][ kbuf 4x8KB | vbuf 4x8KB ] = 2 x 64KB
  int wgid = ((blockIdx.x & 7) << 5) + (blockIdx.x >> 3);  // bijective, 256 = 8*32
  int qt = wgid & 7;
  int bh = wgid >> 3;
  int b = bh >> 4, hh = bh & 15;
  int tid = threadIdx.x, lane = tid & 63, wid = tid >> 6;  // wid 0..15
  int grp = wid >> 3, w8 = wid & 7;
  int l31 = lane & 31, h2 = lane >> 5;
  char* kbuf = lds + grp * 65536;
  char* vbuf = kbuf + 32768;

  // group g covers global key-tiles g*16 + t (t = 0..15)
  const char* kbase = (const char*)k_ws + (long)bh * 2048 * 128 + (long)grp * 131072;
  const char* vbase = (const char*)v_ws + (long)bh * 64 * 4096 + (long)grp * 2048;

  int srow = w8 * 8 + (lane >> 3);
  int scb = ((lane & 7) * 16) ^ (((lane >> 3) & 7) << 4);

#define STAGE(t_) do {                                                              \
    gll16(kbase + ((long)(t_) * 64 + srow) * 128 + scb,                             \
          kbuf + ((t_) & 3) * 8192 + w8 * 1024);                                    \
    gll16(vbase + (long)srow * 4096 + (long)(t_) * 128 + scb,                       \
          vbuf + ((t_) & 3) * 8192 + w8 * 1024);                                    \
  } while (0)

#define WAIT2_BAR do {                                                              \
    asm volatile("s_waitcnt vmcnt(2)" ::: "memory");                                \
    __builtin_amdgcn_s_barrier();                                                   \
    asm volatile("" ::: "memory");                                                  \
  } while (0)

  // fragment byte offsets, shared by K (index=dt) and V (index=c); +4096 for 2nd 32-row tile
  int rofs = l31 * 128, swz = (lane & 7) << 4, h16 = h2 << 4;
  int fof[4];
#pragma unroll
  for (int m = 0; m < 4; m++) fof[m] = rofs + ((32 * m + h16) ^ swz);

  // Q B-fragments: lane (q=l31, h2) holds Q[q][16*dt + 8*h2 + j]
  const bf16* qrow = q_ws + ((long)bh * 2048 + qt * 256 + w8 * 32 + l31) * 64 + 8 * h2;
  short8 qreg[4];
#pragma unroll
  for (int dt = 0; dt < 4; dt++) qreg[dt] = *(const short8*)(qrow + 16 * dt);

  floatx16 sa0, sa1;           // S^T scores: 2 key-tiles x 16 regs
  floatx16 o0 = {}, o1 = {};   // O^T accum: 2 dv-tiles x 16 regs
  short8 pb[4];
  float ls[4] = {0.f, 0.f, 0.f, 0.f};

#define QKSTEP(kc) do {                                                             \
    __builtin_amdgcn_s_setprio(1);                                                  \
    _Pragma("unroll") for (int dt_ = 0; dt_ < 4; dt_++) {                           \
      short8 ka_ = *(const short8*)((kc) + fof[dt_]);                               \
      short8 kb_ = *(const short8*)((kc) + 4096 + fof[dt_]);                        \
      if (dt_ == 0) {                                                               \
        sa0 = __builtin_amdgcn_mfma_f32_32x32x16_bf16(ka_, qreg[0], (floatx16){}, 0, 0, 0); \
        sa1 = __builtin_amdgcn_mfma_f32_32x32x16_bf16(kb_, qreg[0], (floatx16){}, 0, 0, 0); \
      } else {                                                                      \
        sa0 = __builtin_amdgcn_mfma_f32_32x32x16_bf16(ka_, qreg[dt_], sa0, 0, 0, 0);\
        sa1 = __builtin_amdgcn_mfma_f32_32x32x16_bf16(kb_, qreg[dt_], sa1, 0, 0, 0);\
      }                                                                             \
    }                                                                               \
    __builtin_amdgcn_s_setprio(0);                                                  \
  } while (0)

  // max-free softmax: P = exp2(S); kappa => pb[c] = consecutive 8 sa regs.
#define SMSTEP do {                                                                 \
    if (__builtin_expect(ls[0] > 1e30f, 0)) {                                       \
      const float c_ = 7.8886091e-31f; /* 2^-100 */                                 \
      _Pragma("unroll") for (int i_ = 0; i_ < 4; i_++) ls[i_] *= c_;                \
      _Pragma("unroll") for (int i_ = 0; i_ < 16; i_++) { o0[i_] *= c_; o1[i_] *= c_; } \
    }                                                                               \
    { union { bf16 hh_[8]; short8 s_; } u_;                                         \
      _Pragma("unroll") for (int j_ = 0; j_ < 8; j_++) {                            \
        float e_ = fast_exp2(sa0[j_]); ls[j_ & 3] += e_; u_.hh_[j_] = (bf16)e_; }   \
      pb[0] = u_.s_;                                                                \
      _Pragma("unroll") for (int j_ = 0; j_ < 8; j_++) {                            \
        float e_ = fast_exp2(sa0[8 + j_]); ls[j_ & 3] += e_; u_.hh_[j_] = (bf16)e_; } \
      pb[1] = u_.s_;                                                                \
      _Pragma("unroll") for (int j_ = 0; j_ < 8; j_++) {                            \
        float e_ = fast_exp2(sa1[j_]); ls[j_ & 3] += e_; u_.hh_[j_] = (bf16)e_; }   \
      pb[2] = u_.s_;                                                                \
      _Pragma("unroll") for (int j_ = 0; j_ < 8; j_++) {                            \
        float e_ = fast_exp2(sa1[8 + j_]); ls[j_ & 3] += e_; u_.hh_[j_] = (bf16)e_; } \
      pb[3] = u_.s_;                                                                \
    }                                                                               \
  } while (0)

#define PVSTEP(vc) do {                                                             \
    __builtin_amdgcn_s_setprio(1);                                                  \
    _Pragma("unroll") for (int c_ = 0; c_ < 4; c_++) {                              \
      short8 va_ = *(const short8*)((vc) + fof[c_]);                                \
      short8 vb_ = *(const short8*)((vc) + 4096 + fof[c_]);                         \
      o0 = __builtin_amdgcn_mfma_f32_32x32x16_bf16(va_, pb[c_], o0, 0, 0, 0);       \
      o1 = __builtin_amdgcn_mfma_f32_32x32x16_bf16(vb_, pb[c_], o1, 0, 0, 0);       \
    }                                                                               \
    __builtin_amdgcn_s_setprio(0);                                                  \
  } while (0)

  // ---- prologue ----
  STAGE(0); STAGE(1);
  WAIT2_BAR;                   // tile 0 landed (tile 1 in flight)
  QKSTEP(kbuf + 0 * 8192);     // sa(0)
  STAGE(2);

  // ---- legs t = 0..12 ----
  for (int t = 0; t <= 12; t++) {
    SMSTEP;                    // pb(t)
    PVSTEP(vbuf + (t & 3) * 8192);
    WAIT2_BAR;                 // tile t+1 landed (t+2 in flight)
    STAGE(t + 3);
    QKSTEP(kbuf + ((t + 1) & 3) * 8192);
  }
  // ---- leg 13 (no stage) ----
  SMSTEP;
  PVSTEP(vbuf + (13 & 3) * 8192);
  WAIT2_BAR;                   // tile 14 landed (15 in flight)
  QKSTEP(kbuf + (14 & 3) * 8192);
  // ---- leg 14 (drain) ----
  SMSTEP;
  PVSTEP(vbuf + (14 & 3) * 8192);
  asm volatile("s_waitcnt vmcnt(0)" ::: "memory");
  __builtin_amdgcn_s_barrier();
  QKSTEP(kbuf + (15 & 3) * 8192);
  // ---- leg 15 ----
  SMSTEP;
  PVSTEP(vbuf + (15 & 3) * 8192);

#undef STAGE
#undef WAIT2_BAR
#undef QKSTEP
#undef SMSTEP
#undef PVSTEP

  // ---- combine: O = O0 + O1, l = l0 + l1 through dead LDS ----
  __syncthreads();
  float lsum = (ls[0] + ls[1]) + (ls[2] + ls[3]);
  float lpair = lsum + __shfl_xor(lsum, 32);   // merge h-halves (per q, per group)
  int sq = qt * 256 + w8 * 32 + l31;
  if (grp == 1) {
    char* pk = lds + 65536 + w8 * 8192;        // group 1's own dead K/V region
    *(floatx16*)(pk + lane * 64) = o0;
    *(floatx16*)(pk + 4096 + lane * 64) = o1;
    if (h2 == 0) *(float*)(lds + (w8 * 32 + l31) * 4) = lpair;
  }
  __syncthreads();
  if (grp == 0) {
    const char* pk = lds + 65536 + w8 * 8192;
    floatx16 a0 = *(const floatx16*)(pk + lane * 64);
    floatx16 a1 = *(const floatx16*)(pk + 4096 + lane * 64);
    float lp = *(const float*)(lds + (w8 * 32 + l31) * 4);
    float inv = 1.f / (lpair + lp);
    bf16* orow = obuf + ((long)b * 2048 + sq) * 1024 + hh * 64;
#pragma unroll
    for (int rg = 0; rg < 4; rg++) {
      union { bf16 hv[4]; short4v s4; } uo;
#pragma unroll
      for (int i = 0; i < 4; i++) uo.hv[i] = (bf16)((o0[4 * rg + i] + a0[4 * rg + i]) * inv);
      *(short4v*)(orow + 8 * rg + 4 * h2) = uo.s4;
#pragma unroll
      for (int i = 0; i < 4; i++) uo.hv[i] = (bf16)((o1[4 * rg + i] + a1[4 * rg + i]) * inv);
      *(short4v*)(orow + 32 + 8 * rg + 4 * h2) = uo.s4;
    }
  }
}

// ---------------- launch ----------------
extern "C" void kernel_launch(void* const* d_in, const int* in_sizes, int n_in,
                              void* d_out, int out_size, void* d_ws, size_t ws_size,
                              hipStream_t stream) {
  const float* x  = (const float*)d_in[0];
  const float* Wq = (const float*)d_in[1];
  const float* Wk = (const float*)d_in[2];
  const float* Wv = (const float*)d_in[3];
  const float* Wo = (const float*)d_in[4];
  float* out = (float*)d_out;

  char* ws = (char*)d_ws;
  bf16* x_bf  = (bf16*)(ws);                    // 8 MiB
  bf16* WbigT = (bf16*)(ws + 8388608);          // 6 MiB
  bf16* WoT   = (bf16*)(ws + 14680064);         // 2 MiB
  bf16* q_ws  = (bf16*)(ws + 16777216);         // 8 MiB
  bf16* k_ws  = (bf16*)(ws + 25165824);         // 8 MiB
  bf16* v_ws  = (bf16*)(ws + 33554432);         // 8 MiB
  bf16* obuf  = (bf16*)(ws + 41943040);         // 8 MiB (total 48 MiB)

  hipFuncSetAttribute((const void*)gemm256_qkv,
                      hipFuncAttributeMaxDynamicSharedMemorySize, 131072);
  hipFuncSetAttribute((const void*)attn_kernel,
                      hipFuncAttributeMaxDynamicSharedMemorySize, 131072);

  prep_all<<<3072, 256, 0, stream>>>(x, Wq, Wk, Wv, Wo, x_bf, WbigT, WoT);
  gemm256_qkv<<<192, 512, 131072, stream>>>(x_bf, WbigT, q_ws, k_ws, v_ws);
  attn_kernel<<<256, 1024, 131072, stream>>>(q_ws, k_ws, v_ws, obuf);
  gemm_out<<<256, 256, 0, stream>>>(obuf, WoT, out, 1024, 8);
}

// Round 11
// 105.041 us; speedup vs baseline: 1.0654x; 1.0654x over previous
//
#include <hip/hip_runtime.h>

typedef __bf16 bf16;
typedef __attribute__((ext_vector_type(8))) short short8;
typedef __attribute__((ext_vector_type(4))) short short4v;
typedef __attribute__((ext_vector_type(4))) float floatx4;
typedef __attribute__((ext_vector_type(16))) float floatx16;

#define DEVINL __device__ __forceinline__

// async global->LDS, 16B per lane. LDS dest = wave-uniform base + lane*16.
DEVINL void gll16(const void* g, void* l) {
  __builtin_amdgcn_global_load_lds((const __attribute__((address_space(1))) void*)g,
                                   (__attribute__((address_space(3))) void*)l, 16, 0, 0);
}

DEVINL float fast_exp2(float x) { return __builtin_amdgcn_exp2f(x); }

// scale * log2(e), folded into Q at projection time
#define QSCALE 0.18033688011112042f

// ---------------- fused prep: x->bf16 (blocks 0..2047) + weight transposes (2048..3071) ----
__global__ __launch_bounds__(256) void prep_all(const float* __restrict__ x,
                                                const float* __restrict__ Wq,
                                                const float* __restrict__ Wk,
                                                const float* __restrict__ Wv,
                                                const float* __restrict__ Wo,
                                                bf16* __restrict__ x_bf,
                                                bf16* __restrict__ WbigT,
                                                bf16* __restrict__ WoT) {
  __shared__ float tile[64][65];
  int bid = blockIdx.x;
  if (bid < 2048) {
    int i = (bid * 256 + threadIdx.x) * 8;
    float4 a = *(const float4*)(x + i);
    float4 b = *(const float4*)(x + i + 4);
    union { bf16 h[8]; short8 s; } u;
    u.h[0] = (bf16)a.x; u.h[1] = (bf16)a.y; u.h[2] = (bf16)a.z; u.h[3] = (bf16)a.w;
    u.h[4] = (bf16)b.x; u.h[5] = (bf16)b.y; u.h[6] = (bf16)b.z; u.h[7] = (bf16)b.w;
    *(short8*)(x_bf + i) = u.s;
    return;
  }
  int t = bid - 2048;
  int which = t >> 8;         // 0..3
  t &= 255;
  const float* in;
  bf16* out;
  int C, tilesC, tilesPerBatch;
  long inStride;
  if (which < 3) {
    in = which == 0 ? Wq : (which == 1 ? Wk : Wv);
    out = WbigT + (long)which * 1024 * 1024;
    C = 64; tilesC = 1; tilesPerBatch = 16; inStride = 65536;
  } else {
    in = Wo; out = WoT;
    C = 1024; tilesC = 16; tilesPerBatch = 256; inStride = 0;
  }
  int batch = t / tilesPerBatch;
  int tt = t % tilesPerBatch;
  int ri = tt / tilesC, ci = tt % tilesC;
  const float* src = in + batch * inStride;
  bf16* dst = out + batch * (long)65536 * (which < 3 ? 1 : 0);
  int tx = threadIdx.x & 63, ty = threadIdx.x >> 6;
#pragma unroll
  for (int i = 0; i < 16; i++) {
    int r = ty + i * 4;
    tile[r][tx] = src[(long)(ri * 64 + r) * C + ci * 64 + tx];
  }
  __syncthreads();
#pragma unroll
  for (int i = 0; i < 16; i++) {
    int c = ty + i * 4;
    dst[(long)(ci * 64 + c) * 1024 + ri * 64 + tx] = (bf16)tile[tx][c];
  }
}

// ---------------- QKV GEMM: 256x256 tile, BK=64, 8-phase counted-vmcnt schedule --------
__global__ __launch_bounds__(512, 2) void gemm256_qkv(const bf16* __restrict__ A,
                                                      const bf16* __restrict__ BT,
                                                      bf16* __restrict__ q_ws,
                                                      bf16* __restrict__ k_ws,
                                                      bf16* __restrict__ v_ws) {
  extern __shared__ char lds[];
  int swz = (blockIdx.x & 7) * 24 + (blockIdx.x >> 3);  // grid 192 = 16 x 12, XCD swizzle
  int bm = swz / 12, bn = swz % 12;
  int tid = threadIdx.x, lane = tid & 63, wid = tid >> 6;
  int wm = wid >> 2, wn = wid & 3;
  int ql = lane & 15, g = lane >> 4;
  int sw = (ql & 7) << 4;
  int hB = wn >> 1;
  char* ldsA = lds;            // [slot][half] 2*2*16KB
  char* ldsB = lds + 65536;

  const char* Abase = (const char*)A + (long)bm * 256 * 2048;
  const char* Bbase = (const char*)BT + (long)bn * 256 * 2048;
  int scb = ((tid & 7) * 16) ^ (((tid >> 3) & 7) << 4);  // pre-swizzled source col

  floatx4 acc[8][4] = {};
  short8 aF[4], bF[4];

#define STG(dst0, src0, kt_, h_) do {                                              \
    _Pragma("unroll") for (int j_ = 0; j_ < 2; j_++)                               \
      gll16((src0) + (long)((h_) * 128 + j_ * 64 + (tid >> 3)) * 2048              \
                   + (kt_) * 128 + scb,                                            \
            (dst0) + ((kt_) & 1) * 32768 + (h_) * 16384 + j_ * 8192 + wid * 1024); \
  } while (0)
#define LDA(slot_, frh_, kk_) do {                                                 \
    _Pragma("unroll") for (int j_ = 0; j_ < 4; j_++)                               \
      aF[j_] = *(const short8*)(ldsA + (slot_) * 32768 + wm * 16384 +              \
               (((frh_) * 4 + j_) * 16 + ql) * 128 + (((kk_) * 64 + g * 16) ^ sw));\
  } while (0)
#define LDB(slot_, kk_) do {                                                       \
    _Pragma("unroll") for (int f_ = 0; f_ < 4; f_++)                               \
      bF[f_] = *(const short8*)(ldsB + (slot_) * 32768 + hB * 16384 +              \
               ((wn & 1) * 64 + f_ * 16 + ql) * 128 + (((kk_) * 64 + g * 16) ^ sw));\
  } while (0)
#define MFMA16(frh_) do {                                                          \
    __builtin_amdgcn_s_setprio(1);                                                 \
    _Pragma("unroll") for (int j_ = 0; j_ < 4; j_++)                               \
      _Pragma("unroll") for (int f_ = 0; f_ < 4; f_++)                             \
        acc[(frh_) * 4 + j_][f_] = __builtin_amdgcn_mfma_f32_16x16x32_bf16(        \
            aF[j_], bF[f_], acc[(frh_) * 4 + j_][f_], 0, 0, 0);                    \
    __builtin_amdgcn_s_setprio(0);                                                 \
  } while (0)
#define BAR __builtin_amdgcn_s_barrier()
#define LG0 asm volatile("s_waitcnt lgkmcnt(0)" ::: "memory")

  // prologue: B0(0),B1(0),A0(0),A1(0),B0(1) = 10 loads
  STG(ldsB, Bbase, 0, 0); STG(ldsB, Bbase, 0, 1);
  STG(ldsA, Abase, 0, 0); STG(ldsA, Abase, 0, 1);
  STG(ldsB, Bbase, 1, 0);

  for (int it = 0; it < 8; it++) {
    int b1 = 2 * it + 1, a2 = 2 * it + 2, b2 = 2 * it + 3;
    bool more = it < 7;
    // P1 (a, frh0, kk0)
    asm volatile("s_waitcnt vmcnt(2)" ::: "memory");
    BAR;
    LDA(0, 0, 0); LDB(0, 0);
    STG(ldsA, Abase, b1, 0);
    BAR; LG0; MFMA16(0); BAR;
    // P2 (a, frh1, kk0)
    LDA(0, 1, 0);
    STG(ldsA, Abase, b1, 1);
    BAR; LG0; MFMA16(1); BAR;
    // P3 (a, frh0, kk1)
    LDA(0, 0, 1); LDB(0, 1);
    STG(ldsB, Bbase, b1, 1);
    BAR; LG0; MFMA16(0); BAR;
    // P4 (a, frh1, kk1)
    LDA(0, 1, 1);
    if (more) STG(ldsB, Bbase, a2, 0);
    BAR; LG0; MFMA16(1); BAR;
    // P5 (b, frh0, kk0)
    if (more) { asm volatile("s_waitcnt vmcnt(2)" ::: "memory"); }
    else      { asm volatile("s_waitcnt vmcnt(0)" ::: "memory"); }
    BAR;
    LDA(1, 0, 0); LDB(1, 0);
    if (more) STG(ldsB, Bbase, a2, 1);
    BAR; LG0; MFMA16(0); BAR;
    // P6 (b, frh1, kk0)
    LDA(1, 1, 0);
    if (more) STG(ldsA, Abase, a2, 0);
    BAR; LG0; MFMA16(1); BAR;
    // P7 (b, frh0, kk1)
    LDA(1, 0, 1); LDB(1, 1);
    if (more) STG(ldsA, Abase, a2, 1);
    BAR; LG0; MFMA16(0); BAR;
    // P8 (b, frh1, kk1)
    LDA(1, 1, 1);
    if (more) STG(ldsB, Bbase, b2, 0);
    BAR; LG0; MFMA16(1); BAR;
  }
#undef STG
#undef LDA
#undef LDB
#undef MFMA16
#undef BAR
#undef LG0

  if (bn < 8) {
    // ---- Q / K scatter ----
    bf16* dst = (bn < 4) ? q_ws : k_ws;
    float scale = (bn < 4) ? QSCALE : 1.0f;
#pragma unroll
    for (int fr = 0; fr < 8; fr++)
#pragma unroll
      for (int fc = 0; fc < 4; fc++)
#pragma unroll
        for (int i = 0; i < 4; i++) {
          int r = bm * 256 + wm * 128 + fr * 16 + g * 4 + i;
          int c = bn * 256 + wn * 64 + fc * 16 + ql;
          int b = r >> 11, s = r & 2047;
          int h = (c >> 6) & 15, e = c & 63;
          long bh = (long)b * 16 + h;
          dst[(bh * 2048 + s) * 64 + e] = (bf16)(acc[fr][fc][i] * scale);
        }
  } else {
    // ---- V: acc -> LDS (sigma32 = swap key bits 2<->3, + swizzle) -> coalesced V^T stores ----
#pragma unroll
    for (int fr = 0; fr < 8; fr++)
#pragma unroll
      for (int fc = 0; fc < 4; fc++) {
        int local_c = wn * 64 + fc * 16 + ql;        // 0..255 (dv within block)
        int ls0 = wm * 128 + fr * 16 + g * 4;        // 0..255 (s local, 4-aligned)
        // sigma32: swap bits 2 and 3 of the key index
        int sp = (ls0 & ~12) | ((ls0 & 4) << 1) | ((ls0 & 8) >> 1);
        union { bf16 hh[4]; short4v s4; } u;
#pragma unroll
        for (int i = 0; i < 4; i++) u.hh[i] = (bf16)acc[fr][fc][i];
        *(short4v*)(lds + local_c * 512 + ((sp * 2) ^ ((local_c & 7) << 4))) = u.s4;
      }
    __syncthreads();
    int b = bm >> 3;
    long sbase = (long)(bm & 7) * 256;
#pragma unroll
    for (int j = 0; j < 16; j++) {
      int local_c = wid * 32 + j * 2 + (lane >> 5);
      int chunk = lane & 31;
      int cg = bn * 256 + local_c;                   // 2048..3071
      int h = (cg >> 6) & 15, e = cg & 63;
      long bh = (long)b * 16 + h;
      char* dstp = (char*)v_ws + ((bh * 64 + e) * 2048 + sbase) * 2 + chunk * 16;
      *(short8*)dstp = *(const short8*)(lds + local_c * 512 + ((chunk * 16) ^ ((local_c & 7) << 4)));
    }
  }
}

// ---------------- GEMM (output projection): 128x128 tile, 4 waves, 2-phase pipelined ----
__global__ __launch_bounds__(256) void gemm_out(const bf16* __restrict__ A,
                                                const bf16* __restrict__ BT,
                                                float* __restrict__ Cout,
                                                int N, int gridN) {
  int cpx = gridDim.x >> 3;
  int swz = (blockIdx.x & 7) * cpx + (blockIdx.x >> 3);
  int bm = swz / gridN, bn = swz % gridN;
  __shared__ char lds[65536];  // A slots @0,16K ; B slots @32K,48K
  int tid = threadIdx.x;
  int lane = tid & 63, wid = tid >> 6;
  int wr = wid >> 1, wc = wid & 1;
  floatx4 acc[4][4] = {};
  const char* Abase = (const char*)A + (long)bm * 128 * 2048;
  const char* Bbase = (const char*)BT + (long)bn * 128 * 2048;
  int scb = ((tid & 7) * 16) ^ (((tid >> 3) & 7) << 4);

#define OSTG(kt_) do {                                                             \
    char* la_ = lds + ((kt_) & 1) * 16384;                                         \
    char* lb_ = lds + 32768 + ((kt_) & 1) * 16384;                                 \
    _Pragma("unroll") for (int q_ = 0; q_ < 4; q_++) {                             \
      gll16(Abase + (long)(q_ * 32 + (tid >> 3)) * 2048 + (kt_) * 128 + scb,       \
            la_ + q_ * 4096 + wid * 1024);                                         \
      gll16(Bbase + (long)(q_ * 32 + (tid >> 3)) * 2048 + (kt_) * 128 + scb,       \
            lb_ + q_ * 4096 + wid * 1024);                                         \
    }                                                                              \
  } while (0)

  OSTG(0);
  for (int kt = 0; kt < 16; kt++) {
    if (kt < 15) {
      OSTG(kt + 1);
      asm volatile("s_waitcnt vmcnt(8)" ::: "memory");
    } else {
      asm volatile("s_waitcnt vmcnt(0)" ::: "memory");
    }
    __builtin_amdgcn_s_barrier();
    char* la = lds + (kt & 1) * 16384;
    char* lb = lds + 32768 + (kt & 1) * 16384;
#pragma unroll
    for (int kk = 0; kk < 2; kk++) {
      short8 a[4], b[4];
#pragma unroll
      for (int mi = 0; mi < 4; mi++) {
        int row = wr * 64 + mi * 16 + (lane & 15);
        int col = (kk * 64 + (lane >> 4) * 16) ^ ((row & 7) << 4);
        a[mi] = *(const short8*)(la + row * 128 + col);
      }
#pragma unroll
      for (int ni = 0; ni < 4; ni++) {
        int row = wc * 64 + ni * 16 + (lane & 15);
        int col = (kk * 64 + (lane >> 4) * 16) ^ ((row & 7) << 4);
        b[ni] = *(const short8*)(lb + row * 128 + col);
      }
#pragma unroll
      for (int mi = 0; mi < 4; mi++)
#pragma unroll
        for (int ni = 0; ni < 4; ni++)
          acc[mi][ni] = __builtin_amdgcn_mfma_f32_16x16x32_bf16(a[mi], b[ni], acc[mi][ni], 0, 0, 0);
    }
    __builtin_amdgcn_s_barrier();
  }
#undef OSTG

#pragma unroll
  for (int mi = 0; mi < 4; mi++)
#pragma unroll
    for (int ni = 0; ni < 4; ni++)
#pragma unroll
      for (int i = 0; i < 4; i++) {
        int r = bm * 128 + wr * 64 + mi * 16 + (lane >> 4) * 4 + i;
        int c = bn * 128 + wc * 64 + ni * 16 + (lane & 15);
        Cout[(long)r * N + c] = acc[mi][ni][i];
      }
}

// ---------------- flash attention: 32x32x16 MFMA, 512 threads, KV-split x2 (4-wave grps) --
// grid 512 = 32bh x 16qt (XCD-bijective). Block = 8 waves = 2 groups of 4; group g covers
// keys [g*1024, +1024) for the same 128 q-rows (32 q/wave). QBLK=128, KVBLK=32.
// 4-deep K/V buffers: K tile [32 keys][128B] 4KB, V^T tile [64 dv][64B] 4KB -> 64KB LDS
// total -> 2 blocks/CU (16 waves/CU). launch_bounds(512,4) -> VGPR cap 128 (no spills; the
// R10 regression was 64-VGPR spilling at 1024 threads).
// Swizzles (conflict-free, 8-lane-phase verified): K rows S(r)=(r&7)^(r>>3); V rows
// Sv(r)=(r>>1)&3. Max-free softmax (R10-verified kappa/sigma32 math). vmcnt(2)+barrier/leg.
__global__ __launch_bounds__(512, 4) void attn_kernel(const bf16* __restrict__ q_ws,
                                                      const bf16* __restrict__ k_ws,
                                                      const bf16* __restrict__ v_ws,
                                                      bf16* __restrict__ obuf) {
  __shared__ char lds[65536];  // [grp][ kbuf 4x4KB | vbuf 4x4KB ] = 2 x 32KB
  int wgid = ((blockIdx.x & 7) << 6) + (blockIdx.x >> 3);  // bijective, 512 = 8*64
  int qt = wgid & 15;
  int bh = wgid >> 4;
  int b = bh >> 4, hh = bh & 15;
  int tid = threadIdx.x, lane = tid & 63, wid = tid >> 6;  // wid 0..7
  int grp = wid >> 2, w4 = wid & 3;
  int l31 = lane & 31, h2 = lane >> 5;
  char* kbuf = lds + grp * 32768;
  char* vbuf = kbuf + 16384;

  // group g covers global key-tiles (32 keys each) g*32 + t, t = 0..31
  const char* kbase = (const char*)k_ws + (long)bh * 2048 * 128 + (long)grp * 131072;
  const char* vbase = (const char*)v_ws + (long)bh * 64 * 4096 + (long)grp * 2048;

  // K staging: wave w4 covers rows w4*8..+7; lane: row = w4*8 + (lane>>3), slot = lane&7
  int ksrow = w4 * 8 + (lane >> 3);
  int kscb = (((lane & 7) ^ (lane >> 3) ^ w4) << 4);   // src col = slot ^ S(row)
  // V staging: wave w4 covers dv rows w4*16..+15; lane: row = w4*16 + (lane>>2), slot = lane&3
  int vsrow = w4 * 16 + (lane >> 2);
  int vscb = ((((lane & 3) ^ ((lane >> 3) & 3)) << 4));  // src col = slot ^ Sv(row)

#define STAGE(t_) do {                                                              \
    gll16(kbase + ((long)(t_) * 32 + ksrow) * 128 + kscb,                           \
          kbuf + ((t_) & 3) * 4096 + w4 * 1024);                                    \
    gll16(vbase + (long)vsrow * 4096 + (long)(t_) * 64 + vscb,                      \
          vbuf + ((t_) & 3) * 4096 + w4 * 1024);                                    \
  } while (0)

#define WAIT2_BAR do {                                                              \
    asm volatile("s_waitcnt vmcnt(2)" ::: "memory");                                \
    __builtin_amdgcn_s_barrier();                                                   \
    asm volatile("" ::: "memory");                                                  \
  } while (0)

  // fragment byte offsets
  int Sk = ((l31 & 7) ^ (l31 >> 3)) << 4;
  int Sv = ((l31 >> 1) & 3) << 4;
  int fofk[4], fofv[2];
#pragma unroll
  for (int dt = 0; dt < 4; dt++) fofk[dt] = l31 * 128 + ((dt * 32 + 16 * h2) ^ Sk);
#pragma unroll
  for (int c = 0; c < 2; c++) fofv[c] = l31 * 64 + ((c * 32 + 16 * h2) ^ Sv);  // +2048 tile1

  // Q B-fragments: lane (q=l31, h2) holds Q[q][16*dt + 8*h2 + j]
  const bf16* qrow = q_ws + ((long)bh * 2048 + qt * 128 + w4 * 32 + l31) * 64 + 8 * h2;
  short8 qreg[4];
#pragma unroll
  for (int dt = 0; dt < 4; dt++) qreg[dt] = *(const short8*)(qrow + 16 * dt);

  floatx16 sa;                 // S^T scores for one 32-key tile
  floatx16 o0 = {}, o1 = {};   // O^T accum: 2 dv-tiles x 16 regs
  short8 pb[2];
  float ls[4] = {0.f, 0.f, 0.f, 0.f};

#define QKSTEP(kc) do {                                                             \
    __builtin_amdgcn_s_setprio(1);                                                  \
    sa = __builtin_amdgcn_mfma_f32_32x32x16_bf16(                                   \
        *(const short8*)((kc) + fofk[0]), qreg[0], (floatx16){}, 0, 0, 0);          \
    _Pragma("unroll") for (int dt_ = 1; dt_ < 4; dt_++)                             \
      sa = __builtin_amdgcn_mfma_f32_32x32x16_bf16(                                 \
          *(const short8*)((kc) + fofk[dt_]), qreg[dt_], sa, 0, 0, 0);              \
    __builtin_amdgcn_s_setprio(0);                                                  \
  } while (0)

  // max-free softmax: P = exp2(S); kappa => pb[c] = exp2 of sa regs 8c..8c+7
#define SMSTEP do {                                                                 \
    if (__builtin_expect(ls[0] > 1e30f, 0)) {                                       \
      const float c_ = 7.8886091e-31f; /* 2^-100 */                                 \
      _Pragma("unroll") for (int i_ = 0; i_ < 4; i_++) ls[i_] *= c_;                \
      _Pragma("unroll") for (int i_ = 0; i_ < 16; i_++) { o0[i_] *= c_; o1[i_] *= c_; } \
    }                                                                               \
    { union { bf16 hh_[8]; short8 s_; } u_;                                         \
      _Pragma("unroll") for (int j_ = 0; j_ < 8; j_++) {                            \
        float e_ = fast_exp2(sa[j_]); ls[j_ & 3] += e_; u_.hh_[j_] = (bf16)e_; }    \
      pb[0] = u_.s_;                                                                \
      _Pragma("unroll") for (int j_ = 0; j_ < 8; j_++) {                            \
        float e_ = fast_exp2(sa[8 + j_]); ls[j_ & 3] += e_; u_.hh_[j_] = (bf16)e_; }\
      pb[1] = u_.s_;                                                                \
    }                                                                               \
  } while (0)

#define PVSTEP(vc) do {                                                             \
    __builtin_amdgcn_s_setprio(1);                                                  \
    _Pragma("unroll") for (int c_ = 0; c_ < 2; c_++) {                              \
      o0 = __builtin_amdgcn_mfma_f32_32x32x16_bf16(                                 \
          *(const short8*)((vc) + fofv[c_]), pb[c_], o0, 0, 0, 0);                  \
      o1 = __builtin_amdgcn_mfma_f32_32x32x16_bf16(                                 \
          *(const short8*)((vc) + 2048 + fofv[c_]), pb[c_], o1, 0, 0, 0);           \
    }                                                                               \
    __builtin_amdgcn_s_setprio(0);                                                  \
  } while (0)

  // ---- prologue ----
  STAGE(0); STAGE(1);          // 4 loads out
  WAIT2_BAR;                   // tile 0 landed (tile 1 in flight)
  QKSTEP(kbuf + 0 * 4096);     // sa(0)
  STAGE(2);

  // ---- legs t = 0..28 ----
  for (int t = 0; t <= 28; t++) {
    SMSTEP;                    // pb(t)
    PVSTEP(vbuf + (t & 3) * 4096);
    WAIT2_BAR;                 // tile t+1 landed (t+2 in flight)
    STAGE(t + 3);
    QKSTEP(kbuf + ((t + 1) & 3) * 4096);
  }
  // ---- leg 29 (no stage) ----
  SMSTEP;
  PVSTEP(vbuf + (29 & 3) * 4096);
  WAIT2_BAR;                   // tile 30 landed (31 in flight)
  QKSTEP(kbuf + (30 & 3) * 4096);
  // ---- leg 30 (drain) ----
  SMSTEP;
  PVSTEP(vbuf + (30 & 3) * 4096);
  asm volatile("s_waitcnt vmcnt(0)" ::: "memory");
  __builtin_amdgcn_s_barrier();
  QKSTEP(kbuf + (31 & 3) * 4096);
  // ---- leg 31 ----
  SMSTEP;
  PVSTEP(vbuf + (31 & 3) * 4096);

#undef STAGE
#undef WAIT2_BAR
#undef QKSTEP
#undef SMSTEP
#undef PVSTEP

  // ---- combine: O = O0 + O1, l = l0 + l1 through dead LDS ----
  __syncthreads();
  float lsum = (ls[0] + ls[1]) + (ls[2] + ls[3]);
  float lpair = lsum + __shfl_xor(lsum, 32);   // merge h-halves (per q, per group)
  int sq = qt * 128 + w4 * 32 + l31;
  if (grp == 1) {
    char* pk = lds + 32768 + w4 * 8192;        // group 1's own dead K/V region
    *(floatx16*)(pk + lane * 64) = o0;
    *(floatx16*)(pk + 4096 + lane * 64) = o1;
    if (h2 == 0) *(float*)(lds + (w4 * 32 + l31) * 4) = lpair;
  }
  __syncthreads();
  if (grp == 0) {
    const char* pk = lds + 32768 + w4 * 8192;
    floatx16 a0 = *(const floatx16*)(pk + lane * 64);
    floatx16 a1 = *(const floatx16*)(pk + 4096 + lane * 64);
    float lp = *(const float*)(lds + (w4 * 32 + l31) * 4);
    float inv = 1.f / (lpair + lp);
    bf16* orow = obuf + ((long)b * 2048 + sq) * 1024 + hh * 64;
#pragma unroll
    for (int rg = 0; rg < 4; rg++) {
      union { bf16 hv[4]; short4v s4; } uo;
#pragma unroll
      for (int i = 0; i < 4; i++) uo.hv[i] = (bf16)((o0[4 * rg + i] + a0[4 * rg + i]) * inv);
      *(short4v*)(orow + 8 * rg + 4 * h2) = uo.s4;
#pragma unroll
      for (int i = 0; i < 4; i++) uo.hv[i] = (bf16)((o1[4 * rg + i] + a1[4 * rg + i]) * inv);
      *(short4v*)(orow + 32 + 8 * rg + 4 * h2) = uo.s4;
    }
  }
}

// ---------------- launch ----------------
extern "C" void kernel_launch(void* const* d_in, const int* in_sizes, int n_in,
                              void* d_out, int out_size, void* d_ws, size_t ws_size,
                              hipStream_t stream) {
  const float* x  = (const float*)d_in[0];
  const float* Wq = (const float*)d_in[1];
  const float* Wk = (const float*)d_in[2];
  const float* Wv = (const float*)d_in[3];
  const float* Wo = (const float*)d_in[4];
  float* out = (float*)d_out;

  char* ws = (char*)d_ws;
  bf16* x_bf  = (bf16*)(ws);                    // 8 MiB
  bf16* WbigT = (bf16*)(ws + 8388608);          // 6 MiB
  bf16* WoT   = (bf16*)(ws + 14680064);         // 2 MiB
  bf16* q_ws  = (bf16*)(ws + 16777216);         // 8 MiB
  bf16* k_ws  = (bf16*)(ws + 25165824);         // 8 MiB
  bf16* v_ws  = (bf16*)(ws + 33554432);         // 8 MiB
  bf16* obuf  = (bf16*)(ws + 41943040);         // 8 MiB (total 48 MiB)

  hipFuncSetAttribute((const void*)gemm256_qkv,
                      hipFuncAttributeMaxDynamicSharedMemorySize, 131072);

  prep_all<<<3072, 256, 0, stream>>>(x, Wq, Wk, Wv, Wo, x_bf, WbigT, WoT);
  gemm256_qkv<<<192, 512, 131072, stream>>>(x_bf, WbigT, q_ws, k_ws, v_ws);
  attn_kernel<<<512, 512, 0, stream>>>(q_ws, k_ws, v_ws, obuf);
  gemm_out<<<256, 256, 0, stream>>>(obuf, WoT, out, 1024, 8);
}

// Round 12
// 100.411 us; speedup vs baseline: 1.1146x; 1.0461x over previous
//
#include <hip/hip_runtime.h>

typedef __bf16 bf16;
typedef __attribute__((ext_vector_type(8))) short short8;
typedef __attribute__((ext_vector_type(4))) short short4v;
typedef __attribute__((ext_vector_type(4))) float floatx4;

#define DEVINL __device__ __forceinline__

// async global->LDS, 16B per lane. LDS dest = wave-uniform base + lane*16.
DEVINL void gll16(const void* g, void* l) {
  __builtin_amdgcn_global_load_lds((const __attribute__((address_space(1))) void*)g,
                                   (__attribute__((address_space(3))) void*)l, 16, 0, 0);
}

DEVINL float fast_exp2(float x) { return __builtin_amdgcn_exp2f(x); }

// scale * log2(e), folded into Q at projection time
#define QSCALE 0.18033688011112042f

// ---------------- fused prep: x->bf16 (blocks 0..2047) + weight transposes (2048..3071) ----
__global__ __launch_bounds__(256) void prep_all(const float* __restrict__ x,
                                                const float* __restrict__ Wq,
                                                const float* __restrict__ Wk,
                                                const float* __restrict__ Wv,
                                                const float* __restrict__ Wo,
                                                bf16* __restrict__ x_bf,
                                                bf16* __restrict__ WbigT,
                                                bf16* __restrict__ WoT) {
  __shared__ float tile[64][65];
  int bid = blockIdx.x;
  if (bid < 2048) {
    int i = (bid * 256 + threadIdx.x) * 8;
    float4 a = *(const float4*)(x + i);
    float4 b = *(const float4*)(x + i + 4);
    union { bf16 h[8]; short8 s; } u;
    u.h[0] = (bf16)a.x; u.h[1] = (bf16)a.y; u.h[2] = (bf16)a.z; u.h[3] = (bf16)a.w;
    u.h[4] = (bf16)b.x; u.h[5] = (bf16)b.y; u.h[6] = (bf16)b.z; u.h[7] = (bf16)b.w;
    *(short8*)(x_bf + i) = u.s;
    return;
  }
  int t = bid - 2048;
  int which = t >> 8;         // 0..3
  t &= 255;
  const float* in;
  bf16* out;
  int C, tilesC, tilesPerBatch;
  long inStride;
  if (which < 3) {
    in = which == 0 ? Wq : (which == 1 ? Wk : Wv);
    out = WbigT + (long)which * 1024 * 1024;
    C = 64; tilesC = 1; tilesPerBatch = 16; inStride = 65536;
  } else {
    in = Wo; out = WoT;
    C = 1024; tilesC = 16; tilesPerBatch = 256; inStride = 0;
  }
  int batch = t / tilesPerBatch;
  int tt = t % tilesPerBatch;
  int ri = tt / tilesC, ci = tt % tilesC;
  const float* src = in + batch * inStride;
  bf16* dst = out + batch * (long)65536 * (which < 3 ? 1 : 0);
  int tx = threadIdx.x & 63, ty = threadIdx.x >> 6;
#pragma unroll
  for (int i = 0; i < 16; i++) {
    int r = ty + i * 4;
    tile[r][tx] = src[(long)(ri * 64 + r) * C + ci * 64 + tx];
  }
  __syncthreads();
#pragma unroll
  for (int i = 0; i < 16; i++) {
    int c = ty + i * 4;
    dst[(long)(ci * 64 + c) * 1024 + ri * 64 + tx] = (bf16)tile[tx][c];
  }
}

// ---------------- QKV GEMM: 256x256 tile, BK=64, 8-phase counted-vmcnt schedule --------
__global__ __launch_bounds__(512, 2) void gemm256_qkv(const bf16* __restrict__ A,
                                                      const bf16* __restrict__ BT,
                                                      bf16* __restrict__ q_ws,
                                                      bf16* __restrict__ k_ws,
                                                      bf16* __restrict__ v_ws) {
  extern __shared__ char lds[];
  int swz = (blockIdx.x & 7) * 24 + (blockIdx.x >> 3);  // grid 192 = 16 x 12, XCD swizzle
  int bm = swz / 12, bn = swz % 12;
  int tid = threadIdx.x, lane = tid & 63, wid = tid >> 6;
  int wm = wid >> 2, wn = wid & 3;
  int ql = lane & 15, g = lane >> 4;
  int sw = (ql & 7) << 4;
  int hB = wn >> 1;
  char* ldsA = lds;            // [slot][half] 2*2*16KB
  char* ldsB = lds + 65536;

  const char* Abase = (const char*)A + (long)bm * 256 * 2048;
  const char* Bbase = (const char*)BT + (long)bn * 256 * 2048;
  int scb = ((tid & 7) * 16) ^ (((tid >> 3) & 7) << 4);  // pre-swizzled source col

  floatx4 acc[8][4] = {};
  short8 aF[4], bF[4];

#define STG(dst0, src0, kt_, h_) do {                                              \
    _Pragma("unroll") for (int j_ = 0; j_ < 2; j_++)                               \
      gll16((src0) + (long)((h_) * 128 + j_ * 64 + (tid >> 3)) * 2048              \
                   + (kt_) * 128 + scb,                                            \
            (dst0) + ((kt_) & 1) * 32768 + (h_) * 16384 + j_ * 8192 + wid * 1024); \
  } while (0)
#define LDA(slot_, frh_, kk_) do {                                                 \
    _Pragma("unroll") for (int j_ = 0; j_ < 4; j_++)                               \
      aF[j_] = *(const short8*)(ldsA + (slot_) * 32768 + wm * 16384 +              \
               (((frh_) * 4 + j_) * 16 + ql) * 128 + (((kk_) * 64 + g * 16) ^ sw));\
  } while (0)
#define LDB(slot_, kk_) do {                                                       \
    _Pragma("unroll") for (int f_ = 0; f_ < 4; f_++)                               \
      bF[f_] = *(const short8*)(ldsB + (slot_) * 32768 + hB * 16384 +              \
               ((wn & 1) * 64 + f_ * 16 + ql) * 128 + (((kk_) * 64 + g * 16) ^ sw));\
  } while (0)
#define MFMA16(frh_) do {                                                          \
    __builtin_amdgcn_s_setprio(1);                                                 \
    _Pragma("unroll") for (int j_ = 0; j_ < 4; j_++)                               \
      _Pragma("unroll") for (int f_ = 0; f_ < 4; f_++)                             \
        acc[(frh_) * 4 + j_][f_] = __builtin_amdgcn_mfma_f32_16x16x32_bf16(        \
            aF[j_], bF[f_], acc[(frh_) * 4 + j_][f_], 0, 0, 0);                    \
    __builtin_amdgcn_s_setprio(0);                                                 \
  } while (0)
#define BAR __builtin_amdgcn_s_barrier()
#define LG0 asm volatile("s_waitcnt lgkmcnt(0)" ::: "memory")

  // prologue: B0(0),B1(0),A0(0),A1(0),B0(1) = 10 loads
  STG(ldsB, Bbase, 0, 0); STG(ldsB, Bbase, 0, 1);
  STG(ldsA, Abase, 0, 0); STG(ldsA, Abase, 0, 1);
  STG(ldsB, Bbase, 1, 0);

  for (int it = 0; it < 8; it++) {
    int b1 = 2 * it + 1, a2 = 2 * it + 2, b2 = 2 * it + 3;
    bool more = it < 7;
    // P1 (a, frh0, kk0)
    asm volatile("s_waitcnt vmcnt(2)" ::: "memory");
    BAR;
    LDA(0, 0, 0); LDB(0, 0);
    STG(ldsA, Abase, b1, 0);
    BAR; LG0; MFMA16(0); BAR;
    // P2 (a, frh1, kk0)
    LDA(0, 1, 0);
    STG(ldsA, Abase, b1, 1);
    BAR; LG0; MFMA16(1); BAR;
    // P3 (a, frh0, kk1)
    LDA(0, 0, 1); LDB(0, 1);
    STG(ldsB, Bbase, b1, 1);
    BAR; LG0; MFMA16(0); BAR;
    // P4 (a, frh1, kk1)
    LDA(0, 1, 1);
    if (more) STG(ldsB, Bbase, a2, 0);
    BAR; LG0; MFMA16(1); BAR;
    // P5 (b, frh0, kk0)
    if (more) { asm volatile("s_waitcnt vmcnt(2)" ::: "memory"); }
    else      { asm volatile("s_waitcnt vmcnt(0)" ::: "memory"); }
    BAR;
    LDA(1, 0, 0); LDB(1, 0);
    if (more) STG(ldsB, Bbase, a2, 1);
    BAR; LG0; MFMA16(0); BAR;
    // P6 (b, frh1, kk0)
    LDA(1, 1, 0);
    if (more) STG(ldsA, Abase, a2, 0);
    BAR; LG0; MFMA16(1); BAR;
    // P7 (b, frh0, kk1)
    LDA(1, 0, 1); LDB(1, 1);
    if (more) STG(ldsA, Abase, a2, 1);
    BAR; LG0; MFMA16(0); BAR;
    // P8 (b, frh1, kk1)
    LDA(1, 1, 1);
    if (more) STG(ldsB, Bbase, b2, 0);
    BAR; LG0; MFMA16(1); BAR;
  }
#undef STG
#undef LDA
#undef LDB
#undef MFMA16
#undef BAR
#undef LG0

  if (bn < 8) {
    // ---- Q / K scatter ----
    bf16* dst = (bn < 4) ? q_ws : k_ws;
    float scale = (bn < 4) ? QSCALE : 1.0f;
#pragma unroll
    for (int fr = 0; fr < 8; fr++)
#pragma unroll
      for (int fc = 0; fc < 4; fc++)
#pragma unroll
        for (int i = 0; i < 4; i++) {
          int r = bm * 256 + wm * 128 + fr * 16 + g * 4 + i;
          int c = bn * 256 + wn * 64 + fc * 16 + ql;
          int b = r >> 11, s = r & 2047;
          int h = (c >> 6) & 15, e = c & 63;
          long bh = (long)b * 16 + h;
          dst[(bh * 2048 + s) * 64 + e] = (bf16)(acc[fr][fc][i] * scale);
        }
  } else {
    // ---- V: acc -> LDS (sigma16 + swizzle) -> coalesced V^T stores ----
#pragma unroll
    for (int fr = 0; fr < 8; fr++)
#pragma unroll
      for (int fc = 0; fc < 4; fc++) {
        int local_c = wn * 64 + fc * 16 + ql;        // 0..255 (dv within block)
        int ls0 = wm * 128 + fr * 16 + g * 4;        // 0..255 (s local, 4-aligned)
        int s6 = ls0 & 63;
        // sigma16: key 32kk+16b'+4g+r' -> pos 32kk+8g+4b'+r'  (16x16 attn kappa order)
        int sp = (ls0 & ~63) | (s6 & 35) | ((s6 & 12) << 1) | ((s6 & 16) >> 2);
        union { bf16 hh[4]; short4v s4; } u;
#pragma unroll
        for (int i = 0; i < 4; i++) u.hh[i] = (bf16)acc[fr][fc][i];
        *(short4v*)(lds + local_c * 512 + ((sp * 2) ^ ((local_c & 7) << 4))) = u.s4;
      }
    __syncthreads();
    int b = bm >> 3;
    long sbase = (long)(bm & 7) * 256;
#pragma unroll
    for (int j = 0; j < 16; j++) {
      int local_c = wid * 32 + j * 2 + (lane >> 5);
      int chunk = lane & 31;
      int cg = bn * 256 + local_c;                   // 2048..3071
      int h = (cg >> 6) & 15, e = cg & 63;
      long bh = (long)b * 16 + h;
      char* dstp = (char*)v_ws + ((bh * 64 + e) * 2048 + sbase) * 2 + chunk * 16;
      *(short8*)dstp = *(const short8*)(lds + local_c * 512 + ((chunk * 16) ^ ((local_c & 7) << 4)));
    }
  }
}

// ---------------- GEMM (output projection): 128x128 tile, 4 waves, 2-phase pipelined ----
__global__ __launch_bounds__(256) void gemm_out(const bf16* __restrict__ A,
                                                const bf16* __restrict__ BT,
                                                float* __restrict__ Cout,
                                                int N, int gridN) {
  int cpx = gridDim.x >> 3;
  int swz = (blockIdx.x & 7) * cpx + (blockIdx.x >> 3);
  int bm = swz / gridN, bn = swz % gridN;
  __shared__ char lds[65536];  // A slots @0,16K ; B slots @32K,48K
  int tid = threadIdx.x;
  int lane = tid & 63, wid = tid >> 6;
  int wr = wid >> 1, wc = wid & 1;
  floatx4 acc[4][4] = {};
  const char* Abase = (const char*)A + (long)bm * 128 * 2048;
  const char* Bbase = (const char*)BT + (long)bn * 128 * 2048;
  int scb = ((tid & 7) * 16) ^ (((tid >> 3) & 7) << 4);

#define OSTG(kt_) do {                                                             \
    char* la_ = lds + ((kt_) & 1) * 16384;                                         \
    char* lb_ = lds + 32768 + ((kt_) & 1) * 16384;                                 \
    _Pragma("unroll") for (int q_ = 0; q_ < 4; q_++) {                             \
      gll16(Abase + (long)(q_ * 32 + (tid >> 3)) * 2048 + (kt_) * 128 + scb,       \
            la_ + q_ * 4096 + wid * 1024);                                         \
      gll16(Bbase + (long)(q_ * 32 + (tid >> 3)) * 2048 + (kt_) * 128 + scb,       \
            lb_ + q_ * 4096 + wid * 1024);                                         \
    }                                                                              \
  } while (0)

  OSTG(0);
  for (int kt = 0; kt < 16; kt++) {
    if (kt < 15) {
      OSTG(kt + 1);
      asm volatile("s_waitcnt vmcnt(8)" ::: "memory");
    } else {
      asm volatile("s_waitcnt vmcnt(0)" ::: "memory");
    }
    __builtin_amdgcn_s_barrier();
    char* la = lds + (kt & 1) * 16384;
    char* lb = lds + 32768 + (kt & 1) * 16384;
#pragma unroll
    for (int kk = 0; kk < 2; kk++) {
      short8 a[4], b[4];
#pragma unroll
      for (int mi = 0; mi < 4; mi++) {
        int row = wr * 64 + mi * 16 + (lane & 15);
        int col = (kk * 64 + (lane >> 4) * 16) ^ ((row & 7) << 4);
        a[mi] = *(const short8*)(la + row * 128 + col);
      }
#pragma unroll
      for (int ni = 0; ni < 4; ni++) {
        int row = wc * 64 + ni * 16 + (lane & 15);
        int col = (kk * 64 + (lane >> 4) * 16) ^ ((row & 7) << 4);
        b[ni] = *(const short8*)(lb + row * 128 + col);
      }
#pragma unroll
      for (int mi = 0; mi < 4; mi++)
#pragma unroll
        for (int ni = 0; ni < 4; ni++)
          acc[mi][ni] = __builtin_amdgcn_mfma_f32_16x16x32_bf16(a[mi], b[ni], acc[mi][ni], 0, 0, 0);
    }
    __builtin_amdgcn_s_barrier();
  }
#undef OSTG

#pragma unroll
  for (int mi = 0; mi < 4; mi++)
#pragma unroll
    for (int ni = 0; ni < 4; ni++)
#pragma unroll
      for (int i = 0; i < 4; i++) {
        int r = bm * 128 + wr * 64 + mi * 16 + (lane >> 4) * 4 + i;
        int c = bn * 128 + wc * 64 + ni * 16 + (lane & 15);
        Cout[(long)r * N + c] = acc[mi][ni][i];
      }
}

// ---------------- flash attention: KV-split x2 in one 1024-thread block (R9-verified) ----
// grid 256 (1 block/CU, XCD-bijective). Block = 16 waves = 2 groups of 8; group g
// processes keys [g*1024, g*1024+1024) for the SAME 256 q-rows (32 q-rows/wave).
// Max-free softmax (P=exp2(S)); combine additive: O=O0+O1, l=l0+l1 via dead LDS.
// Per-group: 16 legs, 4-deep K/V LDS buffers, counted vmcnt(2) + raw s_barrier per leg.
__global__ __launch_bounds__(1024, 4) void attn_kernel(const bf16* __restrict__ q_ws,
                                                       const bf16* __restrict__ k_ws,
                                                       const bf16* __restrict__ v_ws,
                                                       bf16* __restrict__ obuf) {
  extern __shared__ char lds[];  // [grp][ kbuf 4x8KB | vbuf 4x8KB ] = 2 x 64KB
  int wgid = ((blockIdx.x & 7) << 5) + (blockIdx.x >> 3);  // bijective, 256 = 8*32
  int qt = wgid & 7;
  int bh = wgid >> 3;
  int b = bh >> 4, h = bh & 15;
  int tid = threadIdx.x, lane = tid & 63, wid = tid >> 6;  // wid 0..15
  int grp = wid >> 3, w8 = wid & 7;
  int ql = lane & 15, g = lane >> 4;
  char* kbuf = lds + grp * 65536;
  char* vbuf = kbuf + 32768;

  // group g covers global key-tiles g*16 + t (t = 0..15)
  const char* kbase = (const char*)k_ws + (long)bh * 2048 * 128 + (long)grp * 16 * 64 * 128;
  const char* vbase = (const char*)v_ws + (long)bh * 64 * 4096 + (long)grp * 16 * 128;

  int srow = w8 * 8 + (lane >> 3);
  int scb = ((lane & 7) * 16) ^ (((lane >> 3) & 7) << 4);

#define STAGE(t_) do {                                                              \
    gll16(kbase + ((long)(t_) * 64 + srow) * 128 + scb,                             \
          kbuf + ((t_) & 3) * 8192 + w8 * 1024);                                    \
    gll16(vbase + (long)srow * 4096 + (long)(t_) * 128 + scb,                       \
          vbuf + ((t_) & 3) * 8192 + w8 * 1024);                                    \
  } while (0)

#define WAIT2_BAR do {                                                              \
    asm volatile("s_waitcnt vmcnt(2)" ::: "memory");                                \
    __builtin_amdgcn_s_barrier();                                                   \
    asm volatile("" ::: "memory");                                                  \
  } while (0)

  int sw = (ql & 7) << 4;
  int fof0 = ql * 128 + ((g * 16) ^ sw);        // kk = 0
  int fof1 = ql * 128 + ((64 + g * 16) ^ sw);   // kk = 1

  const bf16* qrowL = q_ws + ((long)bh * 2048 + qt * 256 + w8 * 32 + ql) * 64 + 8 * g;
  short8 qL0 = *(const short8*)(qrowL);
  short8 qL1 = *(const short8*)(qrowL + 32);
  short8 qH0 = *(const short8*)(qrowL + 1024);       // +16 rows
  short8 qH1 = *(const short8*)(qrowL + 1024 + 32);

  union { bf16 hh[8]; short8 s; } uo1;
#pragma unroll
  for (int i = 0; i < 8; i++) uo1.hh[i] = (bf16)1.0f;
  const short8 ones = uo1.s;

  floatx4 lL = {}, lH = {};
  floatx4 oL[4] = {}, oH[4] = {};
  floatx4 saL[4], saH[4];
  short8 pbL[2], pbH[2];

#define QKSTEP(kc) do {                                                             \
    __builtin_amdgcn_s_setprio(1);                                                  \
    _Pragma("unroll") for (int t_ = 0; t_ < 4; t_++) {                              \
      short8 kf = *(const short8*)((kc) + fof0 + t_ * 2048);                        \
      saL[t_] = __builtin_amdgcn_mfma_f32_16x16x32_bf16(kf, qL0, (floatx4){}, 0, 0, 0); \
      saH[t_] = __builtin_amdgcn_mfma_f32_16x16x32_bf16(kf, qH0, (floatx4){}, 0, 0, 0); \
    }                                                                               \
    _Pragma("unroll") for (int t_ = 0; t_ < 4; t_++) {                              \
      short8 kf = *(const short8*)((kc) + fof1 + t_ * 2048);                        \
      saL[t_] = __builtin_amdgcn_mfma_f32_16x16x32_bf16(kf, qL1, saL[t_], 0, 0, 0); \
      saH[t_] = __builtin_amdgcn_mfma_f32_16x16x32_bf16(kf, qH1, saH[t_], 0, 0, 0); \
    }                                                                               \
    __builtin_amdgcn_s_setprio(0);                                                  \
  } while (0)

#define SM_HALF(sa, pb, l_acc, o_acc) do {                                          \
    if (__builtin_expect(l_acc[0] > 1e30f, 0)) {                                    \
      const float c_ = 7.8886091e-31f; /* 2^-100 */                                 \
      _Pragma("unroll") for (int t_ = 0; t_ < 4; t_++)                              \
        _Pragma("unroll") for (int i_ = 0; i_ < 4; i_++) o_acc[t_][i_] *= c_;       \
      _Pragma("unroll") for (int i_ = 0; i_ < 4; i_++) l_acc[i_] *= c_;             \
    }                                                                               \
    _Pragma("unroll") for (int kk_ = 0; kk_ < 2; kk_++) {                           \
      union { bf16 hh[8]; short8 s; } up_;                                          \
      _Pragma("unroll") for (int r_ = 0; r_ < 4; r_++)                              \
        up_.hh[r_] = (bf16)fast_exp2(sa[2 * kk_][r_]);                              \
      _Pragma("unroll") for (int r_ = 0; r_ < 4; r_++)                              \
        up_.hh[4 + r_] = (bf16)fast_exp2(sa[2 * kk_ + 1][r_]);                      \
      pb[kk_] = up_.s;                                                              \
    }                                                                               \
  } while (0)

#define SMSTEP do { SM_HALF(saL, pbL, lL, oL); SM_HALF(saH, pbH, lH, oH); } while (0)

#define PVSTEP(vc) do {                                                             \
    __builtin_amdgcn_s_setprio(1);                                                  \
    lL = __builtin_amdgcn_mfma_f32_16x16x32_bf16(ones, pbL[0], lL, 0, 0, 0);        \
    lL = __builtin_amdgcn_mfma_f32_16x16x32_bf16(ones, pbL[1], lL, 0, 0, 0);        \
    lH = __builtin_amdgcn_mfma_f32_16x16x32_bf16(ones, pbH[0], lH, 0, 0, 0);        \
    lH = __builtin_amdgcn_mfma_f32_16x16x32_bf16(ones, pbH[1], lH, 0, 0, 0);        \
    _Pragma("unroll") for (int t_ = 0; t_ < 4; t_++) {                              \
      short8 vf = *(const short8*)((vc) + fof0 + t_ * 2048);                        \
      oL[t_] = __builtin_amdgcn_mfma_f32_16x16x32_bf16(vf, pbL[0], oL[t_], 0, 0, 0);\
      oH[t_] = __builtin_amdgcn_mfma_f32_16x16x32_bf16(vf, pbH[0], oH[t_], 0, 0, 0);\
    }                                                                               \
    _Pragma("unroll") for (int t_ = 0; t_ < 4; t_++) {                              \
      short8 vf = *(const short8*)((vc) + fof1 + t_ * 2048);                        \
      oL[t_] = __builtin_amdgcn_mfma_f32_16x16x32_bf16(vf, pbL[1], oL[t_], 0, 0, 0);\
      oH[t_] = __builtin_amdgcn_mfma_f32_16x16x32_bf16(vf, pbH[1], oH[t_], 0, 0, 0);\
    }                                                                               \
    __builtin_amdgcn_s_setprio(0);                                                  \
  } while (0)

  // ---- prologue ----
  STAGE(0); STAGE(1);
  WAIT2_BAR;
  QKSTEP(kbuf + 0 * 8192);
  STAGE(2);
  SMSTEP;
  WAIT2_BAR;
  STAGE(3);
  QKSTEP(kbuf + 1 * 8192);

  // ---- main loop: legs t = 1..13 ----
  for (int t = 1; t <= 13; t++) {
    PVSTEP(vbuf + ((t - 1) & 3) * 8192);
    SMSTEP;
    WAIT2_BAR;
    if (t <= 12) STAGE(t + 3);
    QKSTEP(kbuf + ((t + 1) & 3) * 8192);
  }

  // ---- leg 14 (drain to 0 for the last tile) ----
  PVSTEP(vbuf + (13 & 3) * 8192);
  SMSTEP;
  __syncthreads();               // vmcnt(0): tile 15 landed
  QKSTEP(kbuf + (15 & 3) * 8192);

  // ---- leg 15 ----
  PVSTEP(vbuf + (14 & 3) * 8192);
  SMSTEP;
  PVSTEP(vbuf + (15 & 3) * 8192);

#undef STAGE
#undef WAIT2_BAR
#undef QKSTEP
#undef SM_HALF
#undef SMSTEP
#undef PVSTEP

  // ---- combine: O = O0 + O1, l = l0 + l1 (all K/V buffers dead) ----
  __syncthreads();
  if (grp == 1) {
    char* pbase = lds + 65536 + w8 * 8192;  // group 1's own (dead) region
#pragma unroll
    for (int t = 0; t < 4; t++) {
      *(floatx4*)(pbase + (t * 2 + 0) * 1024 + lane * 16) = oL[t];
      *(floatx4*)(pbase + (t * 2 + 1) * 1024 + lane * 16) = oH[t];
    }
    *(float2*)(lds + w8 * 512 + lane * 8) = make_float2(lL[0], lH[0]);
  }
  __syncthreads();
  if (grp == 0) {
    float2 lp = *(const float2*)(lds + w8 * 512 + lane * 8);
    const char* pbase = lds + 65536 + w8 * 8192;
    float invL = 1.f / (lL[0] + lp.x);
    float invH = 1.f / (lH[0] + lp.y);
    int s = qt * 256 + w8 * 32 + ql;
    bf16* orowL = obuf + ((long)b * 2048 + s) * 1024 + h * 64;
    bf16* orowH = orowL + 16 * 1024;
#pragma unroll
    for (int t = 0; t < 4; t++) {
      floatx4 aL = *(const floatx4*)(pbase + (t * 2 + 0) * 1024 + lane * 16);
      floatx4 aH = *(const floatx4*)(pbase + (t * 2 + 1) * 1024 + lane * 16);
      union { bf16 hh[4]; short4v s4; } uo;
#pragma unroll
      for (int r = 0; r < 4; r++) uo.hh[r] = (bf16)((oL[t][r] + aL[r]) * invL);
      *(short4v*)(orowL + t * 16 + 4 * g) = uo.s4;
#pragma unroll
      for (int r = 0; r < 4; r++) uo.hh[r] = (bf16)((oH[t][r] + aH[r]) * invH);
      *(short4v*)(orowH + t * 16 + 4 * g) = uo.s4;
    }
  }
}

// ---------------- launch ----------------
extern "C" void kernel_launch(void* const* d_in, const int* in_sizes, int n_in,
                              void* d_out, int out_size, void* d_ws, size_t ws_size,
                              hipStream_t stream) {
  const float* x  = (const float*)d_in[0];
  const float* Wq = (const float*)d_in[1];
  const float* Wk = (const float*)d_in[2];
  const float* Wv = (const float*)d_in[3];
  const float* Wo = (const float*)d_in[4];
  float* out = (float*)d_out;

  char* ws = (char*)d_ws;
  bf16* x_bf  = (bf16*)(ws);                    // 8 MiB
  bf16* WbigT = (bf16*)(ws + 8388608);          // 6 MiB
  bf16* WoT   = (bf16*)(ws + 14680064);         // 2 MiB
  bf16* q_ws  = (bf16*)(ws + 16777216);         // 8 MiB
  bf16* k_ws  = (bf16*)(ws + 25165824);         // 8 MiB
  bf16* v_ws  = (bf16*)(ws + 33554432);         // 8 MiB
  bf16* obuf  = (bf16*)(ws + 41943040);         // 8 MiB (total 48 MiB)

  hipFuncSetAttribute((const void*)gemm256_qkv,
                      hipFuncAttributeMaxDynamicSharedMemorySize, 131072);
  hipFuncSetAttribute((const void*)attn_kernel,
                      hipFuncAttributeMaxDynamicSharedMemorySize, 131072);

  prep_all<<<3072, 256, 0, stream>>>(x, Wq, Wk, Wv, Wo, x_bf, WbigT, WoT);
  gemm256_qkv<<<192, 512, 131072, stream>>>(x_bf, WbigT, q_ws, k_ws, v_ws);
  attn_kernel<<<256, 1024, 131072, stream>>>(q_ws, k_ws, v_ws, obuf);
  gemm_out<<<256, 256, 0, stream>>>(obuf, WoT, out, 1024, 8);
}

// Round 14
// 99.760 us; speedup vs baseline: 1.1218x; 1.0065x over previous
//
#include <hip/hip_runtime.h>

typedef __bf16 bf16;
typedef __attribute__((ext_vector_type(8))) short short8;
typedef __attribute__((ext_vector_type(4))) short short4v;
typedef __attribute__((ext_vector_type(4))) float floatx4;

#define DEVINL __device__ __forceinline__

// async global->LDS, 16B per lane. LDS dest = wave-uniform base + lane*16.
DEVINL void gll16(const void* g, void* l) {
  __builtin_amdgcn_global_load_lds((const __attribute__((address_space(1))) void*)g,
                                   (__attribute__((address_space(3))) void*)l, 16, 0, 0);
}

DEVINL float fast_exp2(float x) { return __builtin_amdgcn_exp2f(x); }

// scale * log2(e), folded into Q at projection time
#define QSCALE 0.18033688011112042f

// ---------------- fused prep: x->bf16 (blocks 0..2047) + weight transposes (2048..3071) ----
__global__ __launch_bounds__(256) void prep_all(const float* __restrict__ x,
                                                const float* __restrict__ Wq,
                                                const float* __restrict__ Wk,
                                                const float* __restrict__ Wv,
                                                const float* __restrict__ Wo,
                                                bf16* __restrict__ x_bf,
                                                bf16* __restrict__ WbigT,
                                                bf16* __restrict__ WoT) {
  __shared__ float tile[64][65];
  int bid = blockIdx.x;
  if (bid < 2048) {
    int i = (bid * 256 + threadIdx.x) * 8;
    float4 a = *(const float4*)(x + i);
    float4 b = *(const float4*)(x + i + 4);
    union { bf16 h[8]; short8 s; } u;
    u.h[0] = (bf16)a.x; u.h[1] = (bf16)a.y; u.h[2] = (bf16)a.z; u.h[3] = (bf16)a.w;
    u.h[4] = (bf16)b.x; u.h[5] = (bf16)b.y; u.h[6] = (bf16)b.z; u.h[7] = (bf16)b.w;
    *(short8*)(x_bf + i) = u.s;
    return;
  }
  int t = bid - 2048;
  int which = t >> 8;         // 0..3
  t &= 255;
  const float* in;
  bf16* out;
  int C, tilesC, tilesPerBatch;
  long inStride;
  if (which < 3) {
    in = which == 0 ? Wq : (which == 1 ? Wk : Wv);
    out = WbigT + (long)which * 1024 * 1024;
    C = 64; tilesC = 1; tilesPerBatch = 16; inStride = 65536;
  } else {
    in = Wo; out = WoT;
    C = 1024; tilesC = 16; tilesPerBatch = 256; inStride = 0;
  }
  int batch = t / tilesPerBatch;
  int tt = t % tilesPerBatch;
  int ri = tt / tilesC, ci = tt % tilesC;
  const float* src = in + batch * inStride;
  bf16* dst = out + batch * (long)65536 * (which < 3 ? 1 : 0);
  int tx = threadIdx.x & 63, ty = threadIdx.x >> 6;
#pragma unroll
  for (int i = 0; i < 16; i++) {
    int r = ty + i * 4;
    tile[r][tx] = src[(long)(ri * 64 + r) * C + ci * 64 + tx];
  }
  __syncthreads();
#pragma unroll
  for (int i = 0; i < 16; i++) {
    int c = ty + i * 4;
    dst[(long)(ci * 64 + c) * 1024 + ri * 64 + tx] = (bf16)tile[tx][c];
  }
}

// ---------------- QKV GEMM: 256x192 tile, BK=64, 8-phase counted-vmcnt schedule --------
// grid 256 = 16M x 16N (full CU fill). 512 threads = 8 waves (2M x 4N); per-wave output
// 128x48 (acc[8][3]). LDS 112KB: A[slot2][half2][16KB] @0, B[slot2][24KB] @64KB.
// RACE-FREE stage placement (R13 post-mortem): a stage into region R is issued only in a
// phase AFTER the barrier following R's last read. Reads: B0@{P1,P3} A0@{P1..P4}
// B1@{P5,P7} A1@{P5..P8}. Stages: P1:A(b1,h0) P2:A(b1,h1) P4:B(a2)x3 P5:A(a2,h0)
// P6:A(a2,h1) P8:B(b2)x3. Waits: vmcnt(3)@P1, vmcnt(3)@P5 (vmcnt(0)@P5 last iter) —
// outstanding-list verified: prologue {B0:3,A0:4,B1:3}; steady 10 in flight at checkpoints.
__global__ __launch_bounds__(512, 2) void gemm256_qkv(const bf16* __restrict__ A,
                                                      const bf16* __restrict__ BT,
                                                      bf16* __restrict__ q_ws,
                                                      bf16* __restrict__ k_ws,
                                                      bf16* __restrict__ v_ws) {
  extern __shared__ char lds[];
  int swz = (blockIdx.x & 7) * 32 + (blockIdx.x >> 3);  // grid 256, XCD swizzle
  int bm = swz >> 4, bn = swz & 15;
  int tid = threadIdx.x, lane = tid & 63, wid = tid >> 6;
  int wm = wid >> 2, wn = wid & 3;
  int ql = lane & 15, g = lane >> 4;
  int sw = (ql & 7) << 4;
  char* ldsA = lds;            // [slot][half] 2*2*16KB = 64KB
  char* ldsB = lds + 65536;    // [slot] 2*24KB = 48KB

  const char* Abase = (const char*)A + (long)bm * 256 * 2048;
  const char* Bbase = (const char*)BT + (long)bn * 192 * 2048;
  int scb = ((tid & 7) * 16) ^ (((tid >> 3) & 7) << 4);  // pre-swizzled source col

  floatx4 acc[8][3] = {};
  short8 aF[4], bF[3];

#define STGA(kt_, h_) do {                                                         \
    _Pragma("unroll") for (int j_ = 0; j_ < 2; j_++)                               \
      gll16(Abase + (long)((h_) * 128 + j_ * 64 + (tid >> 3)) * 2048               \
                   + (kt_) * 128 + scb,                                            \
            ldsA + ((kt_) & 1) * 32768 + (h_) * 16384 + j_ * 8192 + wid * 1024);   \
  } while (0)
#define STGB(kt_, c_)                                                              \
    gll16(Bbase + (long)((c_) * 64 + (tid >> 3)) * 2048 + (kt_) * 128 + scb,       \
          ldsB + ((kt_) & 1) * 24576 + (c_) * 8192 + wid * 1024)
#define LDA(slot_, frh_, kk_) do {                                                 \
    _Pragma("unroll") for (int j_ = 0; j_ < 4; j_++)                               \
      aF[j_] = *(const short8*)(ldsA + (slot_) * 32768 + wm * 16384 +              \
               (((frh_) * 4 + j_) * 16 + ql) * 128 + (((kk_) * 64 + g * 16) ^ sw));\
  } while (0)
#define LDB(slot_, kk_) do {                                                       \
    _Pragma("unroll") for (int f_ = 0; f_ < 3; f_++)                               \
      bF[f_] = *(const short8*)(ldsB + (slot_) * 24576 +                           \
               (wn * 48 + f_ * 16 + ql) * 128 + (((kk_) * 64 + g * 16) ^ sw));     \
  } while (0)
#define MFMA12(frh_) do {                                                          \
    __builtin_amdgcn_s_setprio(1);                                                 \
    _Pragma("unroll") for (int j_ = 0; j_ < 4; j_++)                               \
      _Pragma("unroll") for (int f_ = 0; f_ < 3; f_++)                             \
        acc[(frh_) * 4 + j_][f_] = __builtin_amdgcn_mfma_f32_16x16x32_bf16(        \
            aF[j_], bF[f_], acc[(frh_) * 4 + j_][f_], 0, 0, 0);                    \
    __builtin_amdgcn_s_setprio(0);                                                 \
  } while (0)
#define BAR __builtin_amdgcn_s_barrier()
#define LG0 asm volatile("s_waitcnt lgkmcnt(0)" ::: "memory")

  // prologue: B(0):3, A(0):4, B(1):3 = 10 loads
  STGB(0, 0); STGB(0, 1); STGB(0, 2);
  STGA(0, 0); STGA(0, 1);
  STGB(1, 0); STGB(1, 1); STGB(1, 2);

  for (int it = 0; it < 8; it++) {
    int b1 = 2 * it + 1, a2 = 2 * it + 2, b2 = 2 * it + 3;
    bool more = it < 7;
    // P1 (slot0, frh0, kk0): wait tile a landed (leave B(b):3)
    asm volatile("s_waitcnt vmcnt(3)" ::: "memory");
    BAR;
    LDA(0, 0, 0); LDB(0, 0);
    STGA(b1, 0);                          // -> slot1 A (last read: prev P8, done)
    BAR; LG0; MFMA12(0); BAR;
    // P2 (slot0, frh1, kk0)
    LDA(0, 1, 0);
    STGA(b1, 1);                          // -> slot1 A
    BAR; LG0; MFMA12(1); BAR;
    // P3 (slot0, frh0, kk1) — no stage (B slot0 still being read here)
    LDA(0, 0, 1); LDB(0, 1);
    BAR; LG0; MFMA12(0); BAR;
    // P4 (slot0, frh1, kk1): B slot0 reads done at P3-bar -> stage B(a2)
    LDA(0, 1, 1);
    if (more) { STGB(a2, 0); STGB(a2, 1); STGB(a2, 2); }
    BAR; LG0; MFMA12(1); BAR;
    // P5 (slot1, frh0, kk0): wait tile b landed; A slot0 reads done -> stage A(a2,h0)
    if (more) { asm volatile("s_waitcnt vmcnt(3)" ::: "memory"); }
    else      { asm volatile("s_waitcnt vmcnt(0)" ::: "memory"); }
    BAR;
    LDA(1, 0, 0); LDB(1, 0);
    if (more) STGA(a2, 0);
    BAR; LG0; MFMA12(0); BAR;
    // P6 (slot1, frh1, kk0)
    LDA(1, 1, 0);
    if (more) STGA(a2, 1);
    BAR; LG0; MFMA12(1); BAR;
    // P7 (slot1, frh0, kk1) — no stage (B slot1 still being read here)
    LDA(1, 0, 1); LDB(1, 1);
    BAR; LG0; MFMA12(0); BAR;
    // P8 (slot1, frh1, kk1): B slot1 reads done at P7-bar -> stage B(b2)
    LDA(1, 1, 1);
    if (more) { STGB(b2, 0); STGB(b2, 1); STGB(b2, 2); }
    BAR; LG0; MFMA12(1); BAR;
  }
#undef STGA
#undef STGB
#undef LDA
#undef LDB
#undef MFMA12
#undef BAR
#undef LG0

  // ---- epilogue ----
  // direct scatter for Q/K columns (cg < 2048)
#pragma unroll
  for (int fr = 0; fr < 8; fr++)
#pragma unroll
    for (int fc = 0; fc < 3; fc++) {
      int local_c = wn * 48 + fc * 16 + ql;
      int cg = bn * 192 + local_c;
      if (cg < 2048) {
        bf16* dst = (cg < 1024) ? q_ws : k_ws;
        float scale = (cg < 1024) ? QSCALE : 1.0f;
        int h = (cg >> 6) & 15, e = cg & 63;
#pragma unroll
        for (int i = 0; i < 4; i++) {
          int r = bm * 256 + wm * 128 + fr * 16 + g * 4 + i;
          int b = r >> 11, s = r & 2047;
          long bh = (long)b * 16 + h;
          dst[(bh * 2048 + s) * 64 + e] = (bf16)(acc[fr][fc][i] * scale);
        }
      }
    }

  if (bn >= 10) {
    // ---- V columns (cg >= 2048): acc -> LDS (sigma16 + swizzle) -> coalesced V^T stores
    __syncthreads();   // all MFMA LDS reads long done; reuse lds for transpose
#pragma unroll
    for (int fr = 0; fr < 8; fr++)
#pragma unroll
      for (int fc = 0; fc < 3; fc++) {
        int local_c = wn * 48 + fc * 16 + ql;
        int cg = bn * 192 + local_c;
        if (cg >= 2048) {
          int ls0 = wm * 128 + fr * 16 + g * 4;        // s local, 4-aligned
          int s6 = ls0 & 63;
          // sigma16: key 32kk+16b'+4g+r' -> pos 32kk+8g+4b'+r'
          int sp = (ls0 & ~63) | (s6 & 35) | ((s6 & 12) << 1) | ((s6 & 16) >> 2);
          union { bf16 hh[4]; short4v s4; } u;
#pragma unroll
          for (int i = 0; i < 4; i++) u.hh[i] = (bf16)acc[fr][fc][i];
          *(short4v*)(lds + local_c * 512 + ((sp * 2) ^ ((local_c & 7) << 4))) = u.s4;
        }
      }
    __syncthreads();
    int b = bm >> 3;
    long sbase = (long)(bm & 7) * 256;
#pragma unroll
    for (int j = 0; j < 12; j++) {
      int local_c = wid * 24 + j * 2 + (lane >> 5);
      int cg = bn * 192 + local_c;
      if (cg >= 2048) {
        int chunk = lane & 31;
        int h = (cg >> 6) & 15, e = cg & 63;
        long bh = (long)b * 16 + h;
        char* dstp = (char*)v_ws + ((bh * 64 + e) * 2048 + sbase) * 2 + chunk * 16;
        *(short8*)dstp = *(const short8*)(lds + local_c * 512 + ((chunk * 16) ^ ((local_c & 7) << 4)));
      }
    }
  }
}

// ---------------- GEMM (output projection): 128x128 tile, 4 waves, 2-phase pipelined ----
__global__ __launch_bounds__(256) void gemm_out(const bf16* __restrict__ A,
                                                const bf16* __restrict__ BT,
                                                float* __restrict__ Cout,
                                                int N, int gridN) {
  int cpx = gridDim.x >> 3;
  int swz = (blockIdx.x & 7) * cpx + (blockIdx.x >> 3);
  int bm = swz / gridN, bn = swz % gridN;
  __shared__ char lds[65536];  // A slots @0,16K ; B slots @32K,48K
  int tid = threadIdx.x;
  int lane = tid & 63, wid = tid >> 6;
  int wr = wid >> 1, wc = wid & 1;
  floatx4 acc[4][4] = {};
  const char* Abase = (const char*)A + (long)bm * 128 * 2048;
  const char* Bbase = (const char*)BT + (long)bn * 128 * 2048;
  int scb = ((tid & 7) * 16) ^ (((tid >> 3) & 7) << 4);

#define OSTG(kt_) do {                                                             \
    char* la_ = lds + ((kt_) & 1) * 16384;                                         \
    char* lb_ = lds + 32768 + ((kt_) & 1) * 16384;                                 \
    _Pragma("unroll") for (int q_ = 0; q_ < 4; q_++) {                             \
      gll16(Abase + (long)(q_ * 32 + (tid >> 3)) * 2048 + (kt_) * 128 + scb,       \
            la_ + q_ * 4096 + wid * 1024);                                         \
      gll16(Bbase + (long)(q_ * 32 + (tid >> 3)) * 2048 + (kt_) * 128 + scb,       \
            lb_ + q_ * 4096 + wid * 1024);                                         \
    }                                                                              \
  } while (0)

  OSTG(0);
  for (int kt = 0; kt < 16; kt++) {
    if (kt < 15) {
      OSTG(kt + 1);
      asm volatile("s_waitcnt vmcnt(8)" ::: "memory");
    } else {
      asm volatile("s_waitcnt vmcnt(0)" ::: "memory");
    }
    __builtin_amdgcn_s_barrier();
    char* la = lds + (kt & 1) * 16384;
    char* lb = lds + 32768 + (kt & 1) * 16384;
#pragma unroll
    for (int kk = 0; kk < 2; kk++) {
      short8 a[4], b[4];
#pragma unroll
      for (int mi = 0; mi < 4; mi++) {
        int row = wr * 64 + mi * 16 + (lane & 15);
        int col = (kk * 64 + (lane >> 4) * 16) ^ ((row & 7) << 4);
        a[mi] = *(const short8*)(la + row * 128 + col);
      }
#pragma unroll
      for (int ni = 0; ni < 4; ni++) {
        int row = wc * 64 + ni * 16 + (lane & 15);
        int col = (kk * 64 + (lane >> 4) * 16) ^ ((row & 7) << 4);
        b[ni] = *(const short8*)(lb + row * 128 + col);
      }
#pragma unroll
      for (int mi = 0; mi < 4; mi++)
#pragma unroll
        for (int ni = 0; ni < 4; ni++)
          acc[mi][ni] = __builtin_amdgcn_mfma_f32_16x16x32_bf16(a[mi], b[ni], acc[mi][ni], 0, 0, 0);
    }
    __builtin_amdgcn_s_barrier();
  }
#undef OSTG

#pragma unroll
  for (int mi = 0; mi < 4; mi++)
#pragma unroll
    for (int ni = 0; ni < 4; ni++)
#pragma unroll
      for (int i = 0; i < 4; i++) {
        int r = bm * 128 + wr * 64 + mi * 16 + (lane >> 4) * 4 + i;
        int c = bn * 128 + wc * 64 + ni * 16 + (lane & 15);
        Cout[(long)r * N + c] = acc[mi][ni][i];
      }
}

// ---------------- flash attention: KV-split x2 in one 1024-thread block (R9-verified) ----
__global__ __launch_bounds__(1024, 4) void attn_kernel(const bf16* __restrict__ q_ws,
                                                       const bf16* __restrict__ k_ws,
                                                       const bf16* __restrict__ v_ws,
                                                       bf16* __restrict__ obuf) {
  extern __shared__ char lds[];  // [grp][ kbuf 4x8KB | vbuf 4x8KB ] = 2 x 64KB
  int wgid = ((blockIdx.x & 7) << 5) + (blockIdx.x >> 3);  // bijective, 256 = 8*32
  int qt = wgid & 7;
  int bh = wgid >> 3;
  int b = bh >> 4, h = bh & 15;
  int tid = threadIdx.x, lane = tid & 63, wid = tid >> 6;  // wid 0..15
  int grp = wid >> 3, w8 = wid & 7;
  int ql = lane & 15, g = lane >> 4;
  char* kbuf = lds + grp * 65536;
  char* vbuf = kbuf + 32768;

  const char* kbase = (const char*)k_ws + (long)bh * 2048 * 128 + (long)grp * 16 * 64 * 128;
  const char* vbase = (const char*)v_ws + (long)bh * 64 * 4096 + (long)grp * 16 * 128;

  int srow = w8 * 8 + (lane >> 3);
  int scb = ((lane & 7) * 16) ^ (((lane >> 3) & 7) << 4);

#define STAGE(t_) do {                                                              \
    gll16(kbase + ((long)(t_) * 64 + srow) * 128 + scb,                             \
          kbuf + ((t_) & 3) * 8192 + w8 * 1024);                                    \
    gll16(vbase + (long)srow * 4096 + (long)(t_) * 128 + scb,                       \
          vbuf + ((t_) & 3) * 8192 + w8 * 1024);                                    \
  } while (0)

#define WAIT2_BAR do {                                                              \
    asm volatile("s_waitcnt vmcnt(2)" ::: "memory");                                \
    __builtin_amdgcn_s_barrier();                                                   \
    asm volatile("" ::: "memory");                                                  \
  } while (0)

  int sw = (ql & 7) << 4;
  int fof0 = ql * 128 + ((g * 16) ^ sw);        // kk = 0
  int fof1 = ql * 128 + ((64 + g * 16) ^ sw);   // kk = 1

  const bf16* qrowL = q_ws + ((long)bh * 2048 + qt * 256 + w8 * 32 + ql) * 64 + 8 * g;
  short8 qL0 = *(const short8*)(qrowL);
  short8 qL1 = *(const short8*)(qrowL + 32);
  short8 qH0 = *(const short8*)(qrowL + 1024);       // +16 rows
  short8 qH1 = *(const short8*)(qrowL + 1024 + 32);

  union { bf16 hh[8]; short8 s; } uo1;
#pragma unroll
  for (int i = 0; i < 8; i++) uo1.hh[i] = (bf16)1.0f;
  const short8 ones = uo1.s;

  floatx4 lL = {}, lH = {};
  floatx4 oL[4] = {}, oH[4] = {};
  floatx4 saL[4], saH[4];
  short8 pbL[2], pbH[2];

#define QKSTEP(kc) do {                                                             \
    __builtin_amdgcn_s_setprio(1);                                                  \
    _Pragma("unroll") for (int t_ = 0; t_ < 4; t_++) {                              \
      short8 kf = *(const short8*)((kc) + fof0 + t_ * 2048);                        \
      saL[t_] = __builtin_amdgcn_mfma_f32_16x16x32_bf16(kf, qL0, (floatx4){}, 0, 0, 0); \
      saH[t_] = __builtin_amdgcn_mfma_f32_16x16x32_bf16(kf, qH0, (floatx4){}, 0, 0, 0); \
    }                                                                               \
    _Pragma("unroll") for (int t_ = 0; t_ < 4; t_++) {                              \
      short8 kf = *(const short8*)((kc) + fof1 + t_ * 2048);                        \
      saL[t_] = __builtin_amdgcn_mfma_f32_16x16x32_bf16(kf, qL1, saL[t_], 0, 0, 0); \
      saH[t_] = __builtin_amdgcn_mfma_f32_16x16x32_bf16(kf, qH1, saH[t_], 0, 0, 0); \
    }                                                                               \
    __builtin_amdgcn_s_setprio(0);                                                  \
  } while (0)

#define SM_HALF(sa, pb, l_acc, o_acc) do {                                          \
    if (__builtin_expect(l_acc[0] > 1e30f, 0)) {                                    \
      const float c_ = 7.8886091e-31f; /* 2^-100 */                                 \
      _Pragma("unroll") for (int t_ = 0; t_ < 4; t_++)                              \
        _Pragma("unroll") for (int i_ = 0; i_ < 4; i_++) o_acc[t_][i_] *= c_;       \
      _Pragma("unroll") for (int i_ = 0; i_ < 4; i_++) l_acc[i_] *= c_;             \
    }                                                                               \
    _Pragma("unroll") for (int kk_ = 0; kk_ < 2; kk_++) {                           \
      union { bf16 hh[8]; short8 s; } up_;                                          \
      _Pragma("unroll") for (int r_ = 0; r_ < 4; r_++)                              \
        up_.hh[r_] = (bf16)fast_exp2(sa[2 * kk_][r_]);                              \
      _Pragma("unroll") for (int r_ = 0; r_ < 4; r_++)                              \
        up_.hh[4 + r_] = (bf16)fast_exp2(sa[2 * kk_ + 1][r_]);                      \
      pb[kk_] = up_.s;                                                              \
    }                                                                               \
  } while (0)

#define SMSTEP do { SM_HALF(saL, pbL, lL, oL); SM_HALF(saH, pbH, lH, oH); } while (0)

#define PVSTEP(vc) do {                                                             \
    __builtin_amdgcn_s_setprio(1);                                                  \
    lL = __builtin_amdgcn_mfma_f32_16x16x32_bf16(ones, pbL[0], lL, 0, 0, 0);        \
    lL = __builtin_amdgcn_mfma_f32_16x16x32_bf16(ones, pbL[1], lL, 0, 0, 0);        \
    lH = __builtin_amdgcn_mfma_f32_16x16x32_bf16(ones, pbH[0], lH, 0, 0, 0);        \
    lH = __builtin_amdgcn_mfma_f32_16x16x32_bf16(ones, pbH[1], lH, 0, 0, 0);        \
    _Pragma("unroll") for (int t_ = 0; t_ < 4; t_++) {                              \
      short8 vf = *(const short8*)((vc) + fof0 + t_ * 2048);                        \
      oL[t_] = __builtin_amdgcn_mfma_f32_16x16x32_bf16(vf, pbL[0], oL[t_], 0, 0, 0);\
      oH[t_] = __builtin_amdgcn_mfma_f32_16x16x32_bf16(vf, pbH[0], oH[t_], 0, 0, 0);\
    }                                                                               \
    _Pragma("unroll") for (int t_ = 0; t_ < 4; t_++) {                              \
      short8 vf = *(const short8*)((vc) + fof1 + t_ * 2048);                        \
      oL[t_] = __builtin_amdgcn_mfma_f32_16x16x32_bf16(vf, pbL[1], oL[t_], 0, 0, 0);\
      oH[t_] = __builtin_amdgcn_mfma_f32_16x16x32_bf16(vf, pbH[1], oH[t_], 0, 0, 0);\
    }                                                                               \
    __builtin_amdgcn_s_setprio(0);                                                  \
  } while (0)

  // ---- prologue ----
  STAGE(0); STAGE(1);
  WAIT2_BAR;
  QKSTEP(kbuf + 0 * 8192);
  STAGE(2);
  SMSTEP;
  WAIT2_BAR;
  STAGE(3);
  QKSTEP(kbuf + 1 * 8192);

  // ---- main loop: legs t = 1..13 ----
  for (int t = 1; t <= 13; t++) {
    PVSTEP(vbuf + ((t - 1) & 3) * 8192);
    SMSTEP;
    WAIT2_BAR;
    if (t <= 12) STAGE(t + 3);
    QKSTEP(kbuf + ((t + 1) & 3) * 8192);
  }

  // ---- leg 14 (drain to 0 for the last tile) ----
  PVSTEP(vbuf + (13 & 3) * 8192);
  SMSTEP;
  __syncthreads();               // vmcnt(0): tile 15 landed
  QKSTEP(kbuf + (15 & 3) * 8192);

  // ---- leg 15 ----
  PVSTEP(vbuf + (14 & 3) * 8192);
  SMSTEP;
  PVSTEP(vbuf + (15 & 3) * 8192);

#undef STAGE
#undef WAIT2_BAR
#undef QKSTEP
#undef SM_HALF
#undef SMSTEP
#undef PVSTEP

  // ---- combine: O = O0 + O1, l = l0 + l1 (all K/V buffers dead) ----
  __syncthreads();
  if (grp == 1) {
    char* pbase = lds + 65536 + w8 * 8192;  // group 1's own (dead) region
#pragma unroll
    for (int t = 0; t < 4; t++) {
      *(floatx4*)(pbase + (t * 2 + 0) * 1024 + lane * 16) = oL[t];
      *(floatx4*)(pbase + (t * 2 + 1) * 1024 + lane * 16) = oH[t];
    }
    *(float2*)(lds + w8 * 512 + lane * 8) = make_float2(lL[0], lH[0]);
  }
  __syncthreads();
  if (grp == 0) {
    float2 lp = *(const float2*)(lds + w8 * 512 + lane * 8);
    const char* pbase = lds + 65536 + w8 * 8192;
    float invL = 1.f / (lL[0] + lp.x);
    float invH = 1.f / (lH[0] + lp.y);
    int s = qt * 256 + w8 * 32 + ql;
    bf16* orowL = obuf + ((long)b * 2048 + s) * 1024 + h * 64;
    bf16* orowH = orowL + 16 * 1024;
#pragma unroll
    for (int t = 0; t < 4; t++) {
      floatx4 aL = *(const floatx4*)(pbase + (t * 2 + 0) * 1024 + lane * 16);
      floatx4 aH = *(const floatx4*)(pbase + (t * 2 + 1) * 1024 + lane * 16);
      union { bf16 hh[4]; short4v s4; } uo;
#pragma unroll
      for (int r = 0; r < 4; r++) uo.hh[r] = (bf16)((oL[t][r] + aL[r]) * invL);
      *(short4v*)(orowL + t * 16 + 4 * g) = uo.s4;
#pragma unroll
      for (int r = 0; r < 4; r++) uo.hh[r] = (bf16)((oH[t][r] + aH[r]) * invH);
      *(short4v*)(orowH + t * 16 + 4 * g) = uo.s4;
    }
  }
}

// ---------------- launch ----------------
extern "C" void kernel_launch(void* const* d_in, const int* in_sizes, int n_in,
                              void* d_out, int out_size, void* d_ws, size_t ws_size,
                              hipStream_t stream) {
  const float* x  = (const float*)d_in[0];
  const float* Wq = (const float*)d_in[1];
  const float* Wk = (const float*)d_in[2];
  const float* Wv = (const float*)d_in[3];
  const float* Wo = (const float*)d_in[4];
  float* out = (float*)d_out;

  char* ws = (char*)d_ws;
  bf16* x_bf  = (bf16*)(ws);                    // 8 MiB
  bf16* WbigT = (bf16*)(ws + 8388608);          // 6 MiB
  bf16* WoT   = (bf16*)(ws + 14680064);         // 2 MiB
  bf16* q_ws  = (bf16*)(ws + 16777216);         // 8 MiB
  bf16* k_ws  = (bf16*)(ws + 25165824);         // 8 MiB
  bf16* v_ws  = (bf16*)(ws + 33554432);         // 8 MiB
  bf16* obuf  = (bf16*)(ws + 41943040);         // 8 MiB (total 48 MiB)

  hipFuncSetAttribute((const void*)gemm256_qkv,
                      hipFuncAttributeMaxDynamicSharedMemorySize, 114688);
  hipFuncSetAttribute((const void*)attn_kernel,
                      hipFuncAttributeMaxDynamicSharedMemorySize, 131072);

  prep_all<<<3072, 256, 0, stream>>>(x, Wq, Wk, Wv, Wo, x_bf, WbigT, WoT);
  gemm256_qkv<<<256, 512, 114688, stream>>>(x_bf, WbigT, q_ws, k_ws, v_ws);
  attn_kernel<<<256, 1024, 131072, stream>>>(q_ws, k_ws, v_ws, obuf);
  gemm_out<<<256, 256, 0, stream>>>(obuf, WoT, out, 1024, 8);
}